// Round 1
// baseline (1978.717 us; speedup 1.0000x reference)
//
#include <hip/hip_runtime.h>
#include <cstdint>
#include <cstddef>

// Problem constants (match reference setup_inputs)
#define NN 50000     // nodes
#define EE 1000000   // edges
#define NB 2         // batch
#define LSTR 65      // LDS row stride (floats); 65 % 32 = 1 -> conflict-free

static_assert(EE % 64 == 0, "edge count divisible by 64");

__device__ __forceinline__ float fast_rcp(float v) { return __builtin_amdgcn_rcpf(v); }
__device__ __forceinline__ float silu_f(float v) { return v * fast_rcp(1.0f + __expf(-v)); }
__device__ __forceinline__ float ssgn_f(float v) { return v * fast_rcp(1.0f + fabsf(v)); }

// ---------------------------------------------------------------------------
// Edge kernel: one wave = 64 edges of one batch. lane = edge.
// Computes m = softsign(W2 silu(W1 m_in)), phi, scatters m / weighted / count.
// ---------------------------------------------------------------------------
__global__ __launch_bounds__(256) void edge_kernel(
    const float* __restrict__ h, const float* __restrict__ x,
    const int* __restrict__ ei, const float* __restrict__ ea,
    const float* __restrict__ w_e1, const float* __restrict__ b_e1,
    const float* __restrict__ w_e2, const float* __restrict__ b_e2,
    const float* __restrict__ w_c1, const float* __restrict__ b_c1,
    const float* __restrict__ w_c2,
    const float* __restrict__ sm_p, const float* __restrict__ om_p,
    float* __restrict__ agg,    // [B,N,64]  (aliases d_out h-region; zeroed)
    float* __restrict__ xagg,   // [B,N,4]   (aliases d_out x-region; zeroed)
    float* __restrict__ cnt)    // [N]       (in d_ws; zeroed)
{
    __shared__ float lds_all[4][64 * LSTR];
    const int wid  = threadIdx.x >> 6;
    const int lane = threadIdx.x & 63;
    float* lds = lds_all[wid];

    const int WPB = EE / 64;               // 15625 waves per batch
    const int gw = blockIdx.x * 4 + wid;
    if (gw >= NB * WPB) return;            // no __syncthreads anywhere: safe
    const int b  = gw / WPB;
    const int e0 = (gw - b * WPB) * 64;

    const int row = ei[e0 + lane];
    const int col = ei[EE + e0 + lane];

    // --- radial (Minkowski -,+,+,+) and x rows ---
    const float4 xr = *reinterpret_cast<const float4*>(x + ((size_t)b * NN + row) * 4);
    const float4 xc = *reinterpret_cast<const float4*>(x + ((size_t)b * NN + col) * 4);
    const float d0 = xr.x - xc.x, d1 = xr.y - xc.y, d2 = xr.z - xc.z, d3 = xr.w - xc.w;
    const float radial = d1 * d1 + d2 * d2 + d3 * d3 - d0 * d0;

    // --- edge attributes: 16 contiguous floats per lane (64B line) ---
    float eav[16];
    {
        const float4* eap = reinterpret_cast<const float4*>(ea + ((size_t)b * EE + e0 + lane) * 16);
        #pragma unroll
        for (int j = 0; j < 4; j++) {
            float4 t = eap[j];
            eav[4 * j + 0] = t.x; eav[4 * j + 1] = t.y;
            eav[4 * j + 2] = t.z; eav[4 * j + 3] = t.w;
        }
    }

    const float* hb = h + (size_t)b * NN * 64;

    float acc[64];
    #pragma unroll
    for (int i = 0; i < 64; i++) acc[i] = b_e1[i];

    // ---- GEMM1 part A: h[row] (m_in rows 0..63) ----
    #pragma unroll 8
    for (int e = 0; e < 64; e++) {
        int r = ei[e0 + e];                       // wave-uniform (s_load)
        lds[e * LSTR + lane] = hb[(size_t)r * 64 + lane];  // coalesced row gather
    }
    asm volatile("s_waitcnt lgkmcnt(0)" ::: "memory");
    #pragma unroll 2
    for (int k = 0; k < 64; k++) {
        float mv = lds[lane * LSTR + k];          // own edge, conflict-free
        const float* wr = w_e1 + k * 64;          // wave-uniform -> s_load
        #pragma unroll
        for (int i = 0; i < 64; i++) acc[i] = fmaf(mv, wr[i], acc[i]);
    }
    asm volatile("s_waitcnt lgkmcnt(0)" ::: "memory");

    // ---- GEMM1 part B: h[col] (m_in rows 64..127) ----
    #pragma unroll 8
    for (int e = 0; e < 64; e++) {
        int c = ei[EE + e0 + e];
        lds[e * LSTR + lane] = hb[(size_t)c * 64 + lane];
    }
    asm volatile("s_waitcnt lgkmcnt(0)" ::: "memory");
    #pragma unroll 2
    for (int k = 0; k < 64; k++) {
        float mv = lds[lane * LSTR + k];
        const float* wr = w_e1 + (64 + k) * 64;
        #pragma unroll
        for (int i = 0; i < 64; i++) acc[i] = fmaf(mv, wr[i], acc[i]);
    }

    // ---- GEMM1 part C: radial (row 128) + edge_attr (rows 129..144), registers ----
    {
        const float* wr = w_e1 + 128 * 64;
        #pragma unroll
        for (int i = 0; i < 64; i++) acc[i] = fmaf(radial, wr[i], acc[i]);
    }
    #pragma unroll
    for (int j = 0; j < 16; j++) {
        const float* wj = w_e1 + (129 + j) * 64;
        #pragma unroll
        for (int i = 0; i < 64; i++) acc[i] = fmaf(eav[j], wj[i], acc[i]);
    }

    // ---- silu, stage t1 into own LDS row ----
    #pragma unroll
    for (int i = 0; i < 64; i++) acc[i] = silu_f(acc[i]);
    asm volatile("s_waitcnt lgkmcnt(0)" ::: "memory");
    #pragma unroll
    for (int k = 0; k < 64; k++) lds[lane * LSTR + k] = acc[k];
    asm volatile("s_waitcnt lgkmcnt(0)" ::: "memory");

    // ---- GEMM2: m = softsign(t1 @ w_e2 + b_e2) ----
    float acc2[64];
    #pragma unroll
    for (int i = 0; i < 64; i++) acc2[i] = b_e2[i];
    #pragma unroll 2
    for (int k = 0; k < 64; k++) {
        float mv = lds[lane * LSTR + k];
        const float* wr = w_e2 + k * 64;
        #pragma unroll
        for (int i = 0; i < 64; i++) acc2[i] = fmaf(mv, wr[i], acc2[i]);
    }
    #pragma unroll
    for (int i = 0; i < 64; i++) acc2[i] = ssgn_f(acc2[i]);

    // ---- stage m (used for GEMM3 input and transposed scatter) ----
    asm volatile("s_waitcnt lgkmcnt(0)" ::: "memory");
    #pragma unroll
    for (int k = 0; k < 64; k++) lds[lane * LSTR + k] = acc2[k];
    asm volatile("s_waitcnt lgkmcnt(0)" ::: "memory");

    // ---- GEMM3: phi = silu(m @ w_c1 + b_c1) @ w_c2 ----
    float acc3[64];
    #pragma unroll
    for (int i = 0; i < 64; i++) acc3[i] = b_c1[i];
    #pragma unroll 2
    for (int k = 0; k < 64; k++) {
        float mv = lds[lane * LSTR + k];
        const float* wr = w_c1 + k * 64;
        #pragma unroll
        for (int i = 0; i < 64; i++) acc3[i] = fmaf(mv, wr[i], acc3[i]);
    }
    float phi = 0.0f;
    #pragma unroll
    for (int i = 0; i < 64; i++) phi = fmaf(silu_f(acc3[i]), w_c2[i], phi);

    // ---- scatter m into agg[b, row, :] (transposed: 64 lanes -> one row) ----
    float* aggb = agg + (size_t)b * NN * 64;
    #pragma unroll 4
    for (int e = 0; e < 64; e++) {
        int r = ei[e0 + e];                       // wave-uniform
        atomicAdd(&aggb[(size_t)r * 64 + lane], lds[e * LSTR + lane]);
    }

    // ---- coordinate scatter ----
    const float smv = sm_p[0], omv = om_p[0];
    float* xp = xagg + ((size_t)b * NN + row) * 4;
    atomicAdd(&xp[0], (smv * xr.x + omv * xc.x) * phi);
    atomicAdd(&xp[1], (smv * xr.y + omv * xc.y) * phi);
    atomicAdd(&xp[2], (smv * xr.z + omv * xc.z) * phi);
    atomicAdd(&xp[3], (smv * xr.w + omv * xc.w) * phi);
    if (b == 0) atomicAdd(&cnt[row], 1.0f);
}

// ---------------------------------------------------------------------------
// Node kernel: one wave = 64 nodes of one batch. lane = node.
// h_upd = softsign(silu([h, agg] @ w_f1 + b_f1) @ w_f2 + b_f2)
// x_upd = x + xagg / max(cnt, 1)
// out_h aliases agg, out_x aliases xagg (each wave reads its rows, then writes).
// ---------------------------------------------------------------------------
__global__ __launch_bounds__(256) void node_kernel(
    const float* __restrict__ h, const float* __restrict__ x,
    const float* __restrict__ w_f1, const float* __restrict__ b_f1,
    const float* __restrict__ w_f2, const float* __restrict__ b_f2,
    const float* __restrict__ cnt,
    float* out_h,   // also agg  [B,N,64]
    float* out_x)   // also xagg [B,N,4]
{
    __shared__ float lds_all[4][64 * LSTR];
    const int wid  = threadIdx.x >> 6;
    const int lane = threadIdx.x & 63;
    float* lds = lds_all[wid];

    const int WN = (NN + 63) / 64;   // 782 waves per batch (tail wave: 16 valid)
    const int gw = blockIdx.x * 4 + wid;
    if (gw >= NB * WN) return;
    const int b  = gw / WN;
    const int n0 = (gw - b * WN) * 64;
    const int node = n0 + lane;
    const bool valid = node < NN;

    const float* hb   = h + (size_t)b * NN * 64;
    const float* aggb = out_h + (size_t)b * NN * 64;

    float acc[64];
    #pragma unroll
    for (int i = 0; i < 64; i++) acc[i] = b_f1[i];

    // ---- f_in part A: h rows (w_f1 rows 0..63) ----
    #pragma unroll 8
    for (int e = 0; e < 64; e++) {
        int nd = n0 + e;
        if (nd < NN) lds[e * LSTR + lane] = hb[(size_t)nd * 64 + lane];
    }
    asm volatile("s_waitcnt lgkmcnt(0)" ::: "memory");
    #pragma unroll 2
    for (int k = 0; k < 64; k++) {
        float mv = lds[lane * LSTR + k];
        const float* wr = w_f1 + k * 64;
        #pragma unroll
        for (int i = 0; i < 64; i++) acc[i] = fmaf(mv, wr[i], acc[i]);
    }
    asm volatile("s_waitcnt lgkmcnt(0)" ::: "memory");

    // ---- f_in part B: agg rows (w_f1 rows 64..127) ----
    #pragma unroll 8
    for (int e = 0; e < 64; e++) {
        int nd = n0 + e;
        if (nd < NN) lds[e * LSTR + lane] = aggb[(size_t)nd * 64 + lane];
    }
    asm volatile("s_waitcnt lgkmcnt(0)" ::: "memory");
    #pragma unroll 2
    for (int k = 0; k < 64; k++) {
        float mv = lds[lane * LSTR + k];
        const float* wr = w_f1 + (64 + k) * 64;
        #pragma unroll
        for (int i = 0; i < 64; i++) acc[i] = fmaf(mv, wr[i], acc[i]);
    }

    // ---- silu, stage, GEMM2 ----
    #pragma unroll
    for (int i = 0; i < 64; i++) acc[i] = silu_f(acc[i]);
    asm volatile("s_waitcnt lgkmcnt(0)" ::: "memory");
    #pragma unroll
    for (int k = 0; k < 64; k++) lds[lane * LSTR + k] = acc[k];
    asm volatile("s_waitcnt lgkmcnt(0)" ::: "memory");

    float acc2[64];
    #pragma unroll
    for (int i = 0; i < 64; i++) acc2[i] = b_f2[i];
    #pragma unroll 2
    for (int k = 0; k < 64; k++) {
        float mv = lds[lane * LSTR + k];
        const float* wr = w_f2 + k * 64;
        #pragma unroll
        for (int i = 0; i < 64; i++) acc2[i] = fmaf(mv, wr[i], acc2[i]);
    }
    #pragma unroll
    for (int i = 0; i < 64; i++) acc2[i] = ssgn_f(acc2[i]);

    // ---- transpose via LDS, coalesced store of h_updated ----
    asm volatile("s_waitcnt lgkmcnt(0)" ::: "memory");
    #pragma unroll
    for (int k = 0; k < 64; k++) lds[lane * LSTR + k] = acc2[k];
    asm volatile("s_waitcnt lgkmcnt(0)" ::: "memory");
    float* ohb = out_h + (size_t)b * NN * 64;
    #pragma unroll 8
    for (int e = 0; e < 64; e++) {
        int nd = n0 + e;
        if (nd < NN) ohb[(size_t)nd * 64 + lane] = lds[e * LSTR + lane];
    }

    // ---- x update ----
    if (valid) {
        float c = fmaxf(cnt[node], 1.0f);
        float invc = fast_rcp(c);
        const float4 xv = *reinterpret_cast<const float4*>(x + ((size_t)b * NN + node) * 4);
        float* xop = out_x + ((size_t)b * NN + node) * 4;
        float4 xa = *reinterpret_cast<float4*>(xop);
        float4 r;
        r.x = xv.x + xa.x * invc;
        r.y = xv.y + xa.y * invc;
        r.z = xv.z + xa.z * invc;
        r.w = xv.w + xa.w * invc;
        *reinterpret_cast<float4*>(xop) = r;
    }
}

// ---------------------------------------------------------------------------
extern "C" void kernel_launch(void* const* d_in, const int* in_sizes, int n_in,
                              void* d_out, int out_size, void* d_ws, size_t ws_size,
                              hipStream_t stream) {
    const float* h    = (const float*)d_in[0];
    const float* x    = (const float*)d_in[1];
    const int*   ei   = (const int*)d_in[2];
    const float* ea   = (const float*)d_in[3];
    const float* w_e1 = (const float*)d_in[4];
    const float* b_e1 = (const float*)d_in[5];
    const float* w_e2 = (const float*)d_in[6];
    const float* b_e2 = (const float*)d_in[7];
    const float* w_f1 = (const float*)d_in[8];
    const float* b_f1 = (const float*)d_in[9];
    const float* w_f2 = (const float*)d_in[10];
    const float* b_f2 = (const float*)d_in[11];
    const float* w_c1 = (const float*)d_in[12];
    const float* b_c1 = (const float*)d_in[13];
    const float* w_c2 = (const float*)d_in[14];
    const float* smp  = (const float*)d_in[15];
    const float* omp  = (const float*)d_in[16];

    float* out   = (float*)d_out;
    float* agg   = out;                               // [B,N,64] scratch -> h_updated
    float* out_x = out + (size_t)NB * NN * 64;        // [B,N,4]  scratch -> x_updated
    float* cnt   = (float*)d_ws;                      // [N]

    // zero accumulators (d_out is poisoned before timing; we re-zero every call)
    hipMemsetAsync(d_out, 0, (size_t)out_size * sizeof(float), stream);
    hipMemsetAsync(d_ws, 0, (size_t)NN * sizeof(float), stream);

    const int edge_waves = NB * (EE / 64);            // 31250
    const int edge_blocks = (edge_waves + 3) / 4;     // 7813
    edge_kernel<<<edge_blocks, 256, 0, stream>>>(
        h, x, ei, ea, w_e1, b_e1, w_e2, b_e2, w_c1, b_c1, w_c2,
        smp, omp, agg, out_x, cnt);

    const int node_waves = NB * ((NN + 63) / 64);     // 1564
    const int node_blocks = (node_waves + 3) / 4;     // 391
    node_kernel<<<node_blocks, 256, 0, stream>>>(
        h, x, w_f1, b_f1, w_f2, b_f2, cnt, agg, out_x);
}

// Round 2
// 1074.303 us; speedup vs baseline: 1.8419x; 1.8419x over previous
//
#include <hip/hip_runtime.h>
#include <hip/hip_bf16.h>
#include <cstdint>
#include <cstddef>

#define NN 50000     // nodes
#define EE 1000000   // edges
#define NB 2         // batch
#define LSTR 65      // node-kernel LDS stride (floats)

#define TSTR 40      // tail tile stride (shorts): 80 B rows, 16B-aligned, 2-way banks
#define MSTR 72      // activation tile stride (shorts): 144 B rows, 16B-aligned, 2-way banks

// packed-weight offsets (in shorts): B-fragment order [kstep][ntile][lane][8]
#define P_E1 0        // w_e1: 5 ksteps (K=160, rows permuted: 0..127 h, 128..143 ea, 144 radial)
#define P_E2 10240    // w_e2: 2 ksteps
#define P_C1 14336    // w_c1: 2 ksteps
#define PK_TOTAL 18432
#define WS_PK_OFF 200704  // byte offset of packed weights in d_ws (after cnt[NN])

typedef __attribute__((ext_vector_type(8))) short short8;
typedef __attribute__((ext_vector_type(4))) float f32x4;

__device__ __forceinline__ float fast_rcp(float v) { return __builtin_amdgcn_rcpf(v); }
__device__ __forceinline__ float silu_f(float v) { return v * fast_rcp(1.0f + __expf(-v)); }
__device__ __forceinline__ float ssgn_f(float v) { return v * fast_rcp(1.0f + fabsf(v)); }

__device__ __forceinline__ short f2bf(float f) {
    __hip_bfloat16 h = __float2bfloat16(f);
    return *reinterpret_cast<short*>(&h);
}
__device__ __forceinline__ float bf2f(short s) {
    union { unsigned u; float f; } c; c.u = ((unsigned)(unsigned short)s) << 16; return c.f;
}
__device__ __forceinline__ unsigned pack2(float a, float b) {
    return (unsigned)(unsigned short)f2bf(a) | ((unsigned)(unsigned short)f2bf(b) << 16);
}
__device__ __forceinline__ short8 pack8(float4 a, float4 b) {
    short8 r;
    r[0] = f2bf(a.x); r[1] = f2bf(a.y); r[2] = f2bf(a.z); r[3] = f2bf(a.w);
    r[4] = f2bf(b.x); r[5] = f2bf(b.y); r[6] = f2bf(b.z); r[7] = f2bf(b.w);
    return r;
}

// ---------------------------------------------------------------------------
// Pack weights into MFMA B-fragment order: frag(s,n) lane l short j holds
// B[k = s*32 + (l>>4)*8 + j][col = n*16 + (l&15)], bf16, zero-padded K.
// w_e1 K-rows permuted: k'<128 -> k' (h parts); 128..143 -> ea (orig 129..144);
// 144 -> radial (orig 128); >=145 -> 0.
// ---------------------------------------------------------------------------
__global__ void pack_weights(const float* __restrict__ w_e1,
                             const float* __restrict__ w_e2,
                             const float* __restrict__ w_c1,
                             short* __restrict__ pk)
{
    int g = blockIdx.x * 256 + threadIdx.x;        // one 8-group per thread
    const int G_E1 = 5 * 4 * 64, G_E2 = 2 * 4 * 64, G_C1 = 2 * 4 * 64;
    if (g >= G_E1 + G_E2 + G_C1) return;
    const float* W; int loc; int mat;
    if (g < G_E1)            { W = w_e1; loc = g;               mat = 0; }
    else if (g < G_E1+G_E2)  { W = w_e2; loc = g - G_E1;        mat = 1; }
    else                     { W = w_c1; loc = g - G_E1 - G_E2; mat = 2; }
    int l = loc & 63, n = (loc >> 6) & 3, s = loc >> 8;
    short8 out;
    #pragma unroll
    for (int j = 0; j < 8; j++) {
        int kp = s * 32 + ((l >> 4) * 8) + j;
        int ko; bool valid;
        if (mat == 0) {
            if (kp < 128)      { ko = kp;     valid = true; }
            else if (kp < 144) { ko = kp + 1; valid = true; }   // ea rows 129..144
            else if (kp == 144){ ko = 128;    valid = true; }   // radial row
            else               { ko = 0;      valid = false; }
        } else { ko = kp; valid = kp < 64; }
        float v = valid ? W[ko * 64 + (n * 16 + (l & 15))] : 0.0f;
        out[j] = f2bf(v);
    }
    *reinterpret_cast<short8*>(pk + (size_t)g * 8) = out;
}

// ---------------------------------------------------------------------------
// Edge kernel (MFMA): one wave = 64 edges. 3 GEMMs 64x64 via 16x16x32 bf16.
// ---------------------------------------------------------------------------
__global__ __launch_bounds__(256) void edge_kernel(
    const float* __restrict__ h, const float* __restrict__ x,
    const int* __restrict__ ei, const float* __restrict__ ea,
    const float* __restrict__ b_e1, const float* __restrict__ b_e2,
    const float* __restrict__ b_c1, const float* __restrict__ w_c2,
    const short* __restrict__ pk,
    const float* __restrict__ sm_p, const float* __restrict__ om_p,
    float* __restrict__ agg, float* __restrict__ xagg, float* __restrict__ cnt)
{
    __shared__ short smem[4][64 * MSTR];   // 9216 B per wave
    __shared__ float phis[4][64];
    const int wid  = threadIdx.x >> 6;
    const int lane = threadIdx.x & 63;
    short* sm = smem[wid];
    float* ph = phis[wid];

    const int WPB = EE / 64;
    const int gw = blockIdx.x * 4 + wid;
    if (gw >= NB * WPB) return;            // no barriers anywhere: safe
    const int b  = gw / WPB;
    const int e0 = (gw - b * WPB) * 64;

    const int l15 = lane & 15;
    const int kg  = (lane >> 4) * 8;       // k-offset of this lane's 8-elem group

    const int row = ei[e0 + lane];
    const int col = ei[EE + e0 + lane];
    const float4 xr = *reinterpret_cast<const float4*>(x + ((size_t)b * NN + row) * 4);
    const float4 xc = *reinterpret_cast<const float4*>(x + ((size_t)b * NN + col) * 4);
    const float d0 = xr.x - xc.x, d1 = xr.y - xc.y, d2 = xr.z - xc.z, d3 = xr.w - xc.w;
    const float radial = d1 * d1 + d2 * d2 + d3 * d3 - d0 * d0;

    // ---- stage tail tile [lane][0..15]=ea, [16]=radial, [17..31]=0 (stride TSTR) ----
    {
        const float4* eap = reinterpret_cast<const float4*>(ea + ((size_t)b * EE + e0 + lane) * 16);
        unsigned* dst = reinterpret_cast<unsigned*>(sm + lane * TSTR);
        #pragma unroll
        for (int j = 0; j < 4; j++) {
            float4 t = eap[j];
            dst[2 * j]     = pack2(t.x, t.y);
            dst[2 * j + 1] = pack2(t.z, t.w);
        }
        dst[8] = (unsigned)(unsigned short)f2bf(radial);  // shorts 16(radial),17(0)
        #pragma unroll
        for (int j = 9; j < 16; j++) dst[j] = 0u;         // shorts 18..31 zero
    }
    asm volatile("" ::: "memory");

    // per-lane row indices for the 4 M-tiles
    int rowi[4], coli[4];
    #pragma unroll
    for (int m = 0; m < 4; m++) {
        rowi[m] = ei[e0 + m * 16 + l15];
        coli[m] = ei[EE + e0 + m * 16 + l15];
    }
    const float* hb = h + (size_t)b * NN * 64;

    // ---- GEMM1: m_in[64x160] @ w_e1 -> acc ----
    f32x4 acc[4][4];
    #pragma unroll
    for (int n = 0; n < 4; n++) {
        float bias = b_e1[n * 16 + l15];
        #pragma unroll
        for (int m = 0; m < 4; m++) acc[m][n] = f32x4{bias, bias, bias, bias};
    }
    const short8* pke1 = reinterpret_cast<const short8*>(pk + P_E1);
    #pragma unroll
    for (int s = 0; s < 5; s++) {
        short8 afr[4];
        if (s < 4) {
            #pragma unroll
            for (int m = 0; m < 4; m++) {
                int r = (s < 2) ? rowi[m] : coli[m];
                const float* src = hb + (size_t)r * 64 + (s & 1) * 32 + kg;
                float4 lo = *reinterpret_cast<const float4*>(src);
                float4 hi = *reinterpret_cast<const float4*>(src + 4);
                afr[m] = pack8(lo, hi);
            }
        } else {
            #pragma unroll
            for (int m = 0; m < 4; m++)
                afr[m] = *reinterpret_cast<const short8*>(sm + (m * 16 + l15) * TSTR + kg);
        }
        #pragma unroll
        for (int n = 0; n < 4; n++) {
            short8 bfr = pke1[(s * 4 + n) * 64 + lane];
            #pragma unroll
            for (int m = 0; m < 4; m++)
                acc[m][n] = __builtin_amdgcn_mfma_f32_16x16x32_bf16(afr[m], bfr, acc[m][n], 0, 0, 0);
        }
    }
    asm volatile("" ::: "memory");

    // ---- t1 = silu(acc) -> LDS [64][MSTR] ----
    #pragma unroll
    for (int m = 0; m < 4; m++)
        #pragma unroll
        for (int n = 0; n < 4; n++)
            #pragma unroll
            for (int r = 0; r < 4; r++)
                sm[(m * 16 + (lane >> 4) * 4 + r) * MSTR + n * 16 + l15] = f2bf(silu_f(acc[m][n][r]));
    asm volatile("" ::: "memory");

    // ---- GEMM2: t1 @ w_e2 -> acc2 ----
    f32x4 acc2[4][4];
    #pragma unroll
    for (int n = 0; n < 4; n++) {
        float bias = b_e2[n * 16 + l15];
        #pragma unroll
        for (int m = 0; m < 4; m++) acc2[m][n] = f32x4{bias, bias, bias, bias};
    }
    const short8* pke2 = reinterpret_cast<const short8*>(pk + P_E2);
    #pragma unroll
    for (int s = 0; s < 2; s++) {
        short8 afr[4];
        #pragma unroll
        for (int m = 0; m < 4; m++)
            afr[m] = *reinterpret_cast<const short8*>(sm + (m * 16 + l15) * MSTR + s * 32 + kg);
        #pragma unroll
        for (int n = 0; n < 4; n++) {
            short8 bfr = pke2[(s * 4 + n) * 64 + lane];
            #pragma unroll
            for (int m = 0; m < 4; m++)
                acc2[m][n] = __builtin_amdgcn_mfma_f32_16x16x32_bf16(afr[m], bfr, acc2[m][n], 0, 0, 0);
        }
    }
    asm volatile("" ::: "memory");

    // ---- m = softsign(acc2) -> LDS (overwrites t1) ----
    #pragma unroll
    for (int m = 0; m < 4; m++)
        #pragma unroll
        for (int n = 0; n < 4; n++)
            #pragma unroll
            for (int r = 0; r < 4; r++)
                sm[(m * 16 + (lane >> 4) * 4 + r) * MSTR + n * 16 + l15] = f2bf(ssgn_f(acc2[m][n][r]));
    asm volatile("" ::: "memory");

    // ---- GEMM3: m @ w_c1 -> acc3; phi = silu(acc3) @ w_c2 ----
    f32x4 acc3[4][4];
    #pragma unroll
    for (int n = 0; n < 4; n++) {
        float bias = b_c1[n * 16 + l15];
        #pragma unroll
        for (int m = 0; m < 4; m++) acc3[m][n] = f32x4{bias, bias, bias, bias};
    }
    const short8* pkc1 = reinterpret_cast<const short8*>(pk + P_C1);
    #pragma unroll
    for (int s = 0; s < 2; s++) {
        short8 afr[4];
        #pragma unroll
        for (int m = 0; m < 4; m++)
            afr[m] = *reinterpret_cast<const short8*>(sm + (m * 16 + l15) * MSTR + s * 32 + kg);
        #pragma unroll
        for (int n = 0; n < 4; n++) {
            short8 bfr = pkc1[(s * 4 + n) * 64 + lane];
            #pragma unroll
            for (int m = 0; m < 4; m++)
                acc3[m][n] = __builtin_amdgcn_mfma_f32_16x16x32_bf16(afr[m], bfr, acc3[m][n], 0, 0, 0);
        }
    }
    float wc2v[4];
    #pragma unroll
    for (int n = 0; n < 4; n++) wc2v[n] = w_c2[n * 16 + l15];
    #pragma unroll
    for (int m = 0; m < 4; m++)
        #pragma unroll
        for (int r = 0; r < 4; r++) {
            float v = 0.0f;
            #pragma unroll
            for (int n = 0; n < 4; n++) v = fmaf(silu_f(acc3[m][n][r]), wc2v[n], v);
            v += __shfl_xor(v, 1); v += __shfl_xor(v, 2);
            v += __shfl_xor(v, 4); v += __shfl_xor(v, 8);
            if (l15 == 0) ph[m * 16 + (lane >> 4) * 4 + r] = v;
        }
    asm volatile("" ::: "memory");
    const float phiv = ph[lane];

    // ---- scatter m into agg[b, row_e, :] (lane = feature) ----
    float* aggb = agg + (size_t)b * NN * 64;
    #pragma unroll 4
    for (int e = 0; e < 64; e++) {
        int re = ei[e0 + e];                               // wave-uniform
        float mv = bf2f(sm[e * MSTR + lane]);
        atomicAdd(aggb + (size_t)re * 64 + lane, mv);
    }

    // ---- coordinate scatter (lane = own edge) ----
    const float smv = sm_p[0], omv = om_p[0];
    float* xp = xagg + ((size_t)b * NN + row) * 4;
    atomicAdd(&xp[0], (smv * xr.x + omv * xc.x) * phiv);
    atomicAdd(&xp[1], (smv * xr.y + omv * xc.y) * phiv);
    atomicAdd(&xp[2], (smv * xr.z + omv * xc.z) * phiv);
    atomicAdd(&xp[3], (smv * xr.w + omv * xc.w) * phiv);
    if (b == 0) atomicAdd(&cnt[row], 1.0f);
}

// ---------------------------------------------------------------------------
// Node kernel (unchanged from round 1, f32 VALU)
// ---------------------------------------------------------------------------
__global__ __launch_bounds__(256) void node_kernel(
    const float* __restrict__ h, const float* __restrict__ x,
    const float* __restrict__ w_f1, const float* __restrict__ b_f1,
    const float* __restrict__ w_f2, const float* __restrict__ b_f2,
    const float* __restrict__ cnt,
    float* out_h, float* out_x)
{
    __shared__ float lds_all[4][64 * LSTR];
    const int wid  = threadIdx.x >> 6;
    const int lane = threadIdx.x & 63;
    float* lds = lds_all[wid];

    const int WN = (NN + 63) / 64;
    const int gw = blockIdx.x * 4 + wid;
    if (gw >= NB * WN) return;
    const int b  = gw / WN;
    const int n0 = (gw - b * WN) * 64;
    const int node = n0 + lane;
    const bool valid = node < NN;

    const float* hb   = h + (size_t)b * NN * 64;
    const float* aggb = out_h + (size_t)b * NN * 64;

    float acc[64];
    #pragma unroll
    for (int i = 0; i < 64; i++) acc[i] = b_f1[i];

    #pragma unroll 8
    for (int e = 0; e < 64; e++) {
        int nd = n0 + e;
        if (nd < NN) lds[e * LSTR + lane] = hb[(size_t)nd * 64 + lane];
    }
    asm volatile("s_waitcnt lgkmcnt(0)" ::: "memory");
    #pragma unroll 2
    for (int k = 0; k < 64; k++) {
        float mv = lds[lane * LSTR + k];
        const float* wr = w_f1 + k * 64;
        #pragma unroll
        for (int i = 0; i < 64; i++) acc[i] = fmaf(mv, wr[i], acc[i]);
    }
    asm volatile("s_waitcnt lgkmcnt(0)" ::: "memory");

    #pragma unroll 8
    for (int e = 0; e < 64; e++) {
        int nd = n0 + e;
        if (nd < NN) lds[e * LSTR + lane] = aggb[(size_t)nd * 64 + lane];
    }
    asm volatile("s_waitcnt lgkmcnt(0)" ::: "memory");
    #pragma unroll 2
    for (int k = 0; k < 64; k++) {
        float mv = lds[lane * LSTR + k];
        const float* wr = w_f1 + (64 + k) * 64;
        #pragma unroll
        for (int i = 0; i < 64; i++) acc[i] = fmaf(mv, wr[i], acc[i]);
    }

    #pragma unroll
    for (int i = 0; i < 64; i++) acc[i] = silu_f(acc[i]);
    asm volatile("s_waitcnt lgkmcnt(0)" ::: "memory");
    #pragma unroll
    for (int k = 0; k < 64; k++) lds[lane * LSTR + k] = acc[k];
    asm volatile("s_waitcnt lgkmcnt(0)" ::: "memory");

    float acc2[64];
    #pragma unroll
    for (int i = 0; i < 64; i++) acc2[i] = b_f2[i];
    #pragma unroll 2
    for (int k = 0; k < 64; k++) {
        float mv = lds[lane * LSTR + k];
        const float* wr = w_f2 + k * 64;
        #pragma unroll
        for (int i = 0; i < 64; i++) acc2[i] = fmaf(mv, wr[i], acc2[i]);
    }
    #pragma unroll
    for (int i = 0; i < 64; i++) acc2[i] = ssgn_f(acc2[i]);

    asm volatile("s_waitcnt lgkmcnt(0)" ::: "memory");
    #pragma unroll
    for (int k = 0; k < 64; k++) lds[lane * LSTR + k] = acc2[k];
    asm volatile("s_waitcnt lgkmcnt(0)" ::: "memory");
    float* ohb = out_h + (size_t)b * NN * 64;
    #pragma unroll 8
    for (int e = 0; e < 64; e++) {
        int nd = n0 + e;
        if (nd < NN) ohb[(size_t)nd * 64 + lane] = lds[e * LSTR + lane];
    }

    if (valid) {
        float c = fmaxf(cnt[node], 1.0f);
        float invc = fast_rcp(c);
        const float4 xv = *reinterpret_cast<const float4*>(x + ((size_t)b * NN + node) * 4);
        float* xop = out_x + ((size_t)b * NN + node) * 4;
        float4 xa = *reinterpret_cast<float4*>(xop);
        float4 r;
        r.x = xv.x + xa.x * invc;
        r.y = xv.y + xa.y * invc;
        r.z = xv.z + xa.z * invc;
        r.w = xv.w + xa.w * invc;
        *reinterpret_cast<float4*>(xop) = r;
    }
}

// ---------------------------------------------------------------------------
extern "C" void kernel_launch(void* const* d_in, const int* in_sizes, int n_in,
                              void* d_out, int out_size, void* d_ws, size_t ws_size,
                              hipStream_t stream) {
    const float* h    = (const float*)d_in[0];
    const float* x    = (const float*)d_in[1];
    const int*   ei   = (const int*)d_in[2];
    const float* ea   = (const float*)d_in[3];
    const float* w_e1 = (const float*)d_in[4];
    const float* b_e1 = (const float*)d_in[5];
    const float* w_e2 = (const float*)d_in[6];
    const float* b_e2 = (const float*)d_in[7];
    const float* w_f1 = (const float*)d_in[8];
    const float* b_f1 = (const float*)d_in[9];
    const float* w_f2 = (const float*)d_in[10];
    const float* b_f2 = (const float*)d_in[11];
    const float* w_c1 = (const float*)d_in[12];
    const float* b_c1 = (const float*)d_in[13];
    const float* w_c2 = (const float*)d_in[14];
    const float* smp  = (const float*)d_in[15];
    const float* omp  = (const float*)d_in[16];

    float* out   = (float*)d_out;
    float* agg   = out;                               // [B,N,64] scratch -> h_updated
    float* out_x = out + (size_t)NB * NN * 64;        // [B,N,4]  scratch -> x_updated
    float* cnt   = (float*)d_ws;                      // [N]
    short* pk    = (short*)((char*)d_ws + WS_PK_OFF); // packed bf16 weights

    hipMemsetAsync(d_out, 0, (size_t)out_size * sizeof(float), stream);
    hipMemsetAsync(d_ws, 0, (size_t)NN * sizeof(float), stream);

    pack_weights<<<9, 256, 0, stream>>>(w_e1, w_e2, w_c1, pk);

    const int edge_waves = NB * (EE / 64);            // 31250
    const int edge_blocks = (edge_waves + 3) / 4;     // 7813
    edge_kernel<<<edge_blocks, 256, 0, stream>>>(
        h, x, ei, ea, b_e1, b_e2, b_c1, w_c2, pk,
        smp, omp, agg, out_x, cnt);

    const int node_waves = NB * ((NN + 63) / 64);     // 1564
    const int node_blocks = (node_waves + 3) / 4;     // 391
    node_kernel<<<node_blocks, 256, 0, stream>>>(
        h, x, w_f1, b_f1, w_f2, b_f2, cnt, agg, out_x);
}

// Round 3
// 743.514 us; speedup vs baseline: 2.6613x; 1.4449x over previous
//
#include <hip/hip_runtime.h>
#include <hip/hip_bf16.h>
#include <cstdint>
#include <cstddef>

#define NN 50000     // nodes
#define EE 1000000   // edges
#define NB 2         // batch
#define LSTR 65      // node-kernel LDS stride (floats)

#define TSTR 40      // tail tile stride (shorts): 80 B rows
#define MSTR 72      // activation tile stride (shorts): 144 B rows

// packed-weight layout (shorts)
#define P_E1 0
#define P_E2 10240
#define P_C1 14336

// d_ws byte offsets
#define WS_CNT   0            // int[NN]      histogram
#define WS_OFF   200704       // int[NN+1]    CSR offsets
#define WS_CUR   401408       // int[NN]      scatter cursors
#define WS_EIDS  602112       // int[EE]      row-sorted edge ids
#define WS_PK    4602112      // short[18432] packed bf16 weights
// total ~4.64 MB

typedef __attribute__((ext_vector_type(8))) short short8;
typedef __attribute__((ext_vector_type(4))) float f32x4;

__device__ __forceinline__ float fast_rcp(float v) { return __builtin_amdgcn_rcpf(v); }
__device__ __forceinline__ float silu_f(float v) { return v * fast_rcp(1.0f + __expf(-v)); }
__device__ __forceinline__ float ssgn_f(float v) { return v * fast_rcp(1.0f + fabsf(v)); }

__device__ __forceinline__ short f2bf(float f) {
    __hip_bfloat16 h = __float2bfloat16(f);
    return *reinterpret_cast<short*>(&h);
}
__device__ __forceinline__ float bf2f(short s) {
    union { unsigned u; float f; } c; c.u = ((unsigned)(unsigned short)s) << 16; return c.f;
}
__device__ __forceinline__ unsigned pack2(float a, float b) {
    return (unsigned)(unsigned short)f2bf(a) | ((unsigned)(unsigned short)f2bf(b) << 16);
}
__device__ __forceinline__ short8 pack8(float4 a, float4 b) {
    short8 r;
    r[0] = f2bf(a.x); r[1] = f2bf(a.y); r[2] = f2bf(a.z); r[3] = f2bf(a.w);
    r[4] = f2bf(b.x); r[5] = f2bf(b.y); r[6] = f2bf(b.z); r[7] = f2bf(b.w);
    return r;
}

// ---------------------------------------------------------------------------
// Counting sort of edges by destination row (deterministic per call)
// ---------------------------------------------------------------------------
__global__ void hist_kernel(const int* __restrict__ ei, int* __restrict__ cnt_i) {
    int e = blockIdx.x * 256 + threadIdx.x;
    if (e < EE) atomicAdd(&cnt_i[ei[e]], 1);
}

__global__ void scan_kernel(const int* __restrict__ cnt_i,
                            int* __restrict__ off, int* __restrict__ cur) {
    __shared__ int part[1024];
    const int t = threadIdx.x;
    const int CH = (NN + 1023) / 1024;   // 49
    int base = t * CH;
    int s = 0;
    for (int j = 0; j < CH; j++) { int idx = base + j; if (idx < NN) s += cnt_i[idx]; }
    part[t] = s;
    __syncthreads();
    for (int d = 1; d < 1024; d <<= 1) {
        int v = (t >= d) ? part[t - d] : 0;
        __syncthreads();
        part[t] += v;
        __syncthreads();
    }
    int excl = (t == 0) ? 0 : part[t - 1];
    for (int j = 0; j < CH; j++) {
        int idx = base + j;
        if (idx < NN) { off[idx] = excl; cur[idx] = excl; excl += cnt_i[idx]; }
    }
    if (t == 1023) off[NN] = part[1023];
}

__global__ void scatter_kernel(const int* __restrict__ ei,
                               int* __restrict__ cur, int* __restrict__ eids) {
    int e = blockIdx.x * 256 + threadIdx.x;
    if (e < EE) {
        int p = atomicAdd(&cur[ei[e]], 1);
        eids[p] = e;
    }
}

// ---------------------------------------------------------------------------
// Pack weights into MFMA B-fragment order (same as round 2)
// ---------------------------------------------------------------------------
__global__ void pack_weights(const float* __restrict__ w_e1,
                             const float* __restrict__ w_e2,
                             const float* __restrict__ w_c1,
                             short* __restrict__ pk)
{
    int g = blockIdx.x * 256 + threadIdx.x;
    const int G_E1 = 5 * 4 * 64, G_E2 = 2 * 4 * 64, G_C1 = 2 * 4 * 64;
    if (g >= G_E1 + G_E2 + G_C1) return;
    const float* W; int loc; int mat;
    if (g < G_E1)            { W = w_e1; loc = g;               mat = 0; }
    else if (g < G_E1+G_E2)  { W = w_e2; loc = g - G_E1;        mat = 1; }
    else                     { W = w_c1; loc = g - G_E1 - G_E2; mat = 2; }
    int l = loc & 63, n = (loc >> 6) & 3, s = loc >> 8;
    short8 out;
    #pragma unroll
    for (int j = 0; j < 8; j++) {
        int kp = s * 32 + ((l >> 4) * 8) + j;
        int ko; bool valid;
        if (mat == 0) {
            if (kp < 128)      { ko = kp;     valid = true; }
            else if (kp < 144) { ko = kp + 1; valid = true; }
            else if (kp == 144){ ko = 128;    valid = true; }
            else               { ko = 0;      valid = false; }
        } else { ko = kp; valid = kp < 64; }
        float v = valid ? W[ko * 64 + (n * 16 + (l & 15))] : 0.0f;
        out[j] = f2bf(v);
    }
    *reinterpret_cast<short8*>(pk + (size_t)g * 8) = out;
}

// ---------------------------------------------------------------------------
// Edge kernel (MFMA, row-sorted edge order, run-merged scatters)
// ---------------------------------------------------------------------------
__global__ __launch_bounds__(256) void edge_kernel(
    const float* __restrict__ h, const float* __restrict__ x,
    const int* __restrict__ ei, const float* __restrict__ ea,
    const int* __restrict__ eids,
    const float* __restrict__ b_e1, const float* __restrict__ b_e2,
    const float* __restrict__ b_c1, const float* __restrict__ w_c2,
    const short* __restrict__ pk,
    const float* __restrict__ sm_p, const float* __restrict__ om_p,
    float* __restrict__ agg, float* __restrict__ xagg)
{
    __shared__ short smem[4][64 * MSTR];
    __shared__ float phis[4][64];
    __shared__ int   srow_a[4][64];
    __shared__ int   scol_a[4][64];
    __shared__ int   seid_a[4][64];
    __shared__ float swv_a[4][64 * 4];
    const int wid  = threadIdx.x >> 6;
    const int lane = threadIdx.x & 63;
    short* sm   = smem[wid];
    float* ph   = phis[wid];
    int*   srow = srow_a[wid];
    int*   scol = scol_a[wid];
    int*   seid = seid_a[wid];
    float* swv  = swv_a[wid];

    const int WPB = EE / 64;
    const int gw = blockIdx.x * 4 + wid;
    if (gw >= NB * WPB) return;            // no barriers anywhere: safe
    const int b  = gw / WPB;
    const int i0 = (gw - b * WPB) * 64;    // sorted position base

    const int l15 = lane & 15;
    const int kg  = (lane >> 4) * 8;

    const int eid = eids[i0 + lane];       // coalesced
    const int row = ei[eid];               // gather 4B
    const int col = ei[EE + eid];
    srow[lane] = row; scol[lane] = col; seid[lane] = eid;

    const float4 xr = *reinterpret_cast<const float4*>(x + ((size_t)b * NN + row) * 4);
    const float4 xc = *reinterpret_cast<const float4*>(x + ((size_t)b * NN + col) * 4);
    const float d0 = xr.x - xc.x, d1 = xr.y - xc.y, d2 = xr.z - xc.z, d3 = xr.w - xc.w;
    const float radial = d1 * d1 + d2 * d2 + d3 * d3 - d0 * d0;

    // ---- stage tail tile [lane][0..15]=ea, [16]=radial, rest 0 ----
    {
        const float4* eap = reinterpret_cast<const float4*>(ea + ((size_t)b * EE + eid) * 16);
        unsigned* dst = reinterpret_cast<unsigned*>(sm + lane * TSTR);
        #pragma unroll
        for (int j = 0; j < 4; j++) {
            float4 t = eap[j];
            dst[2 * j]     = pack2(t.x, t.y);
            dst[2 * j + 1] = pack2(t.z, t.w);
        }
        dst[8] = (unsigned)(unsigned short)f2bf(radial);
        #pragma unroll
        for (int j = 9; j < 16; j++) dst[j] = 0u;
    }
    asm volatile("s_waitcnt lgkmcnt(0)" ::: "memory");

    // per-lane row indices for the 4 M-tiles
    int rowi[4], coli[4];
    #pragma unroll
    for (int m = 0; m < 4; m++) {
        rowi[m] = srow[m * 16 + l15];
        coli[m] = scol[m * 16 + l15];
    }
    asm volatile("s_waitcnt lgkmcnt(0)" ::: "memory");
    const float* hb = h + (size_t)b * NN * 64;

    // ---- GEMM1: m_in[64x160] @ w_e1 -> acc ----
    f32x4 acc[4][4];
    #pragma unroll
    for (int n = 0; n < 4; n++) {
        float bias = b_e1[n * 16 + l15];
        #pragma unroll
        for (int m = 0; m < 4; m++) acc[m][n] = f32x4{bias, bias, bias, bias};
    }
    const short8* pke1 = reinterpret_cast<const short8*>(pk + P_E1);
    #pragma unroll
    for (int s = 0; s < 5; s++) {
        short8 afr[4];
        if (s < 4) {
            #pragma unroll
            for (int m = 0; m < 4; m++) {
                int r = (s < 2) ? rowi[m] : coli[m];
                const float* src = hb + (size_t)r * 64 + (s & 1) * 32 + kg;
                float4 lo = *reinterpret_cast<const float4*>(src);
                float4 hi = *reinterpret_cast<const float4*>(src + 4);
                afr[m] = pack8(lo, hi);
            }
        } else {
            #pragma unroll
            for (int m = 0; m < 4; m++)
                afr[m] = *reinterpret_cast<const short8*>(sm + (m * 16 + l15) * TSTR + kg);
        }
        #pragma unroll
        for (int n = 0; n < 4; n++) {
            short8 bfr = pke1[(s * 4 + n) * 64 + lane];
            #pragma unroll
            for (int m = 0; m < 4; m++)
                acc[m][n] = __builtin_amdgcn_mfma_f32_16x16x32_bf16(afr[m], bfr, acc[m][n], 0, 0, 0);
        }
    }
    asm volatile("s_waitcnt lgkmcnt(0)" ::: "memory");

    // ---- t1 = silu(acc) -> LDS ----
    #pragma unroll
    for (int m = 0; m < 4; m++)
        #pragma unroll
        for (int n = 0; n < 4; n++)
            #pragma unroll
            for (int r = 0; r < 4; r++)
                sm[(m * 16 + (lane >> 4) * 4 + r) * MSTR + n * 16 + l15] = f2bf(silu_f(acc[m][n][r]));
    asm volatile("s_waitcnt lgkmcnt(0)" ::: "memory");

    // ---- GEMM2 ----
    f32x4 acc2[4][4];
    #pragma unroll
    for (int n = 0; n < 4; n++) {
        float bias = b_e2[n * 16 + l15];
        #pragma unroll
        for (int m = 0; m < 4; m++) acc2[m][n] = f32x4{bias, bias, bias, bias};
    }
    const short8* pke2 = reinterpret_cast<const short8*>(pk + P_E2);
    #pragma unroll
    for (int s = 0; s < 2; s++) {
        short8 afr[4];
        #pragma unroll
        for (int m = 0; m < 4; m++)
            afr[m] = *reinterpret_cast<const short8*>(sm + (m * 16 + l15) * MSTR + s * 32 + kg);
        #pragma unroll
        for (int n = 0; n < 4; n++) {
            short8 bfr = pke2[(s * 4 + n) * 64 + lane];
            #pragma unroll
            for (int m = 0; m < 4; m++)
                acc2[m][n] = __builtin_amdgcn_mfma_f32_16x16x32_bf16(afr[m], bfr, acc2[m][n], 0, 0, 0);
        }
    }
    asm volatile("s_waitcnt lgkmcnt(0)" ::: "memory");

    // ---- m = softsign(acc2) -> LDS ----
    #pragma unroll
    for (int m = 0; m < 4; m++)
        #pragma unroll
        for (int n = 0; n < 4; n++)
            #pragma unroll
            for (int r = 0; r < 4; r++)
                sm[(m * 16 + (lane >> 4) * 4 + r) * MSTR + n * 16 + l15] = f2bf(ssgn_f(acc2[m][n][r]));
    asm volatile("s_waitcnt lgkmcnt(0)" ::: "memory");

    // ---- GEMM3 + phi ----
    f32x4 acc3[4][4];
    #pragma unroll
    for (int n = 0; n < 4; n++) {
        float bias = b_c1[n * 16 + l15];
        #pragma unroll
        for (int m = 0; m < 4; m++) acc3[m][n] = f32x4{bias, bias, bias, bias};
    }
    const short8* pkc1 = reinterpret_cast<const short8*>(pk + P_C1);
    #pragma unroll
    for (int s = 0; s < 2; s++) {
        short8 afr[4];
        #pragma unroll
        for (int m = 0; m < 4; m++)
            afr[m] = *reinterpret_cast<const short8*>(sm + (m * 16 + l15) * MSTR + s * 32 + kg);
        #pragma unroll
        for (int n = 0; n < 4; n++) {
            short8 bfr = pkc1[(s * 4 + n) * 64 + lane];
            #pragma unroll
            for (int m = 0; m < 4; m++)
                acc3[m][n] = __builtin_amdgcn_mfma_f32_16x16x32_bf16(afr[m], bfr, acc3[m][n], 0, 0, 0);
        }
    }
    float wc2v[4];
    #pragma unroll
    for (int n = 0; n < 4; n++) wc2v[n] = w_c2[n * 16 + l15];
    #pragma unroll
    for (int m = 0; m < 4; m++)
        #pragma unroll
        for (int r = 0; r < 4; r++) {
            float v = 0.0f;
            #pragma unroll
            for (int n = 0; n < 4; n++) v = fmaf(silu_f(acc3[m][n][r]), wc2v[n], v);
            v += __shfl_xor(v, 1); v += __shfl_xor(v, 2);
            v += __shfl_xor(v, 4); v += __shfl_xor(v, 8);
            if (l15 == 0) ph[m * 16 + (lane >> 4) * 4 + r] = v;
        }
    asm volatile("s_waitcnt lgkmcnt(0)" ::: "memory");
    const float phiv = ph[lane];

    // ---- per-lane weighted coordinate, staged to LDS ----
    const float smv = sm_p[0], omv = om_p[0];
    swv[lane * 4 + 0] = (smv * xr.x + omv * xc.x) * phiv;
    swv[lane * 4 + 1] = (smv * xr.y + omv * xc.y) * phiv;
    swv[lane * 4 + 2] = (smv * xr.z + omv * xc.z) * phiv;
    swv[lane * 4 + 3] = (smv * xr.w + omv * xc.w) * phiv;
    asm volatile("s_waitcnt lgkmcnt(0)" ::: "memory");

    // ---- run-merged scatter of m into agg (lane = feature) ----
    float* aggb = agg + (size_t)b * NN * 64;
    {
        float mv = 0.0f;
        for (int e = 0; e < 64; e++) {
            mv += bf2f(sm[e * MSTR + lane]);
            int re = srow[e];
            int rn = (e < 63) ? srow[e + 1] : -1;
            if (re != rn) {
                atomicAdd(aggb + (size_t)re * 64 + lane, mv);
                mv = 0.0f;
            }
        }
    }

    // ---- run-merged coordinate scatter (4 active lanes) ----
    if (lane < 4) {
        float* xb = xagg + (size_t)b * NN * 4;
        float v = 0.0f;
        for (int e = 0; e < 64; e++) {
            v += swv[e * 4 + lane];
            int re = srow[e];
            int rn = (e < 63) ? srow[e + 1] : -1;
            if (re != rn) {
                atomicAdd(xb + (size_t)re * 4 + lane, v);
                v = 0.0f;
            }
        }
    }
}

// ---------------------------------------------------------------------------
// Node kernel (f32 VALU; count from CSR offsets)
// ---------------------------------------------------------------------------
__global__ __launch_bounds__(256) void node_kernel(
    const float* __restrict__ h, const float* __restrict__ x,
    const float* __restrict__ w_f1, const float* __restrict__ b_f1,
    const float* __restrict__ w_f2, const float* __restrict__ b_f2,
    const int* __restrict__ off,
    float* out_h, float* out_x)
{
    __shared__ float lds_all[4][64 * LSTR];
    const int wid  = threadIdx.x >> 6;
    const int lane = threadIdx.x & 63;
    float* lds = lds_all[wid];

    const int WN = (NN + 63) / 64;
    const int gw = blockIdx.x * 4 + wid;
    if (gw >= NB * WN) return;
    const int b  = gw / WN;
    const int n0 = (gw - b * WN) * 64;
    const int node = n0 + lane;
    const bool valid = node < NN;

    const float* hb   = h + (size_t)b * NN * 64;
    const float* aggb = out_h + (size_t)b * NN * 64;

    float acc[64];
    #pragma unroll
    for (int i = 0; i < 64; i++) acc[i] = b_f1[i];

    #pragma unroll 8
    for (int e = 0; e < 64; e++) {
        int nd = n0 + e;
        if (nd < NN) lds[e * LSTR + lane] = hb[(size_t)nd * 64 + lane];
    }
    asm volatile("s_waitcnt lgkmcnt(0)" ::: "memory");
    #pragma unroll 2
    for (int k = 0; k < 64; k++) {
        float mv = lds[lane * LSTR + k];
        const float* wr = w_f1 + k * 64;
        #pragma unroll
        for (int i = 0; i < 64; i++) acc[i] = fmaf(mv, wr[i], acc[i]);
    }
    asm volatile("s_waitcnt lgkmcnt(0)" ::: "memory");

    #pragma unroll 8
    for (int e = 0; e < 64; e++) {
        int nd = n0 + e;
        if (nd < NN) lds[e * LSTR + lane] = aggb[(size_t)nd * 64 + lane];
    }
    asm volatile("s_waitcnt lgkmcnt(0)" ::: "memory");
    #pragma unroll 2
    for (int k = 0; k < 64; k++) {
        float mv = lds[lane * LSTR + k];
        const float* wr = w_f1 + (64 + k) * 64;
        #pragma unroll
        for (int i = 0; i < 64; i++) acc[i] = fmaf(mv, wr[i], acc[i]);
    }

    #pragma unroll
    for (int i = 0; i < 64; i++) acc[i] = silu_f(acc[i]);
    asm volatile("s_waitcnt lgkmcnt(0)" ::: "memory");
    #pragma unroll
    for (int k = 0; k < 64; k++) lds[lane * LSTR + k] = acc[k];
    asm volatile("s_waitcnt lgkmcnt(0)" ::: "memory");

    float acc2[64];
    #pragma unroll
    for (int i = 0; i < 64; i++) acc2[i] = b_f2[i];
    #pragma unroll 2
    for (int k = 0; k < 64; k++) {
        float mv = lds[lane * LSTR + k];
        const float* wr = w_f2 + k * 64;
        #pragma unroll
        for (int i = 0; i < 64; i++) acc2[i] = fmaf(mv, wr[i], acc2[i]);
    }
    #pragma unroll
    for (int i = 0; i < 64; i++) acc2[i] = ssgn_f(acc2[i]);

    asm volatile("s_waitcnt lgkmcnt(0)" ::: "memory");
    #pragma unroll
    for (int k = 0; k < 64; k++) lds[lane * LSTR + k] = acc2[k];
    asm volatile("s_waitcnt lgkmcnt(0)" ::: "memory");
    float* ohb = out_h + (size_t)b * NN * 64;
    #pragma unroll 8
    for (int e = 0; e < 64; e++) {
        int nd = n0 + e;
        if (nd < NN) ohb[(size_t)nd * 64 + lane] = lds[e * LSTR + lane];
    }

    if (valid) {
        int c_i = off[node + 1] - off[node];
        float c = (float)(c_i < 1 ? 1 : c_i);
        float invc = fast_rcp(c);
        const float4 xv = *reinterpret_cast<const float4*>(x + ((size_t)b * NN + node) * 4);
        float* xop = out_x + ((size_t)b * NN + node) * 4;
        float4 xa = *reinterpret_cast<float4*>(xop);
        float4 r;
        r.x = xv.x + xa.x * invc;
        r.y = xv.y + xa.y * invc;
        r.z = xv.z + xa.z * invc;
        r.w = xv.w + xa.w * invc;
        *reinterpret_cast<float4*>(xop) = r;
    }
}

// ---------------------------------------------------------------------------
extern "C" void kernel_launch(void* const* d_in, const int* in_sizes, int n_in,
                              void* d_out, int out_size, void* d_ws, size_t ws_size,
                              hipStream_t stream) {
    const float* h    = (const float*)d_in[0];
    const float* x    = (const float*)d_in[1];
    const int*   ei   = (const int*)d_in[2];
    const float* ea   = (const float*)d_in[3];
    const float* w_e1 = (const float*)d_in[4];
    const float* b_e1 = (const float*)d_in[5];
    const float* w_e2 = (const float*)d_in[6];
    const float* b_e2 = (const float*)d_in[7];
    const float* w_f1 = (const float*)d_in[8];
    const float* b_f1 = (const float*)d_in[9];
    const float* w_f2 = (const float*)d_in[10];
    const float* b_f2 = (const float*)d_in[11];
    const float* w_c1 = (const float*)d_in[12];
    const float* b_c1 = (const float*)d_in[13];
    const float* w_c2 = (const float*)d_in[14];
    const float* smp  = (const float*)d_in[15];
    const float* omp  = (const float*)d_in[16];

    float* out   = (float*)d_out;
    float* agg   = out;                               // [B,N,64] scratch -> h_updated
    float* out_x = out + (size_t)NB * NN * 64;        // [B,N,4]  scratch -> x_updated

    char* ws = (char*)d_ws;
    int*   cnt_i = (int*)(ws + WS_CNT);
    int*   off   = (int*)(ws + WS_OFF);
    int*   cur   = (int*)(ws + WS_CUR);
    int*   eids  = (int*)(ws + WS_EIDS);
    short* pk    = (short*)(ws + WS_PK);

    hipMemsetAsync(d_out, 0, (size_t)out_size * sizeof(float), stream);
    hipMemsetAsync(cnt_i, 0, (size_t)NN * sizeof(int), stream);

    pack_weights<<<9, 256, 0, stream>>>(w_e1, w_e2, w_c1, pk);

    const int eb = (EE + 255) / 256;                  // 3907
    hist_kernel<<<eb, 256, 0, stream>>>(ei, cnt_i);
    scan_kernel<<<1, 1024, 0, stream>>>(cnt_i, off, cur);
    scatter_kernel<<<eb, 256, 0, stream>>>(ei, cur, eids);

    const int edge_waves = NB * (EE / 64);            // 31250
    const int edge_blocks = (edge_waves + 3) / 4;     // 7813
    edge_kernel<<<edge_blocks, 256, 0, stream>>>(
        h, x, ei, ea, eids, b_e1, b_e2, b_c1, w_c2, pk,
        smp, omp, agg, out_x);

    const int node_waves = NB * ((NN + 63) / 64);     // 1564
    const int node_blocks = (node_waves + 3) / 4;     // 391
    node_kernel<<<node_blocks, 256, 0, stream>>>(
        h, x, w_f1, b_f1, w_f2, b_f2, off, agg, out_x);
}

// Round 4
// 575.731 us; speedup vs baseline: 3.4369x; 1.2914x over previous
//
#include <hip/hip_runtime.h>
#include <hip/hip_bf16.h>
#include <cstdint>
#include <cstddef>

#define NN 50000     // nodes
#define EE 1000000   // edges
#define NB 2         // batch

#define MSTR 72      // activation tile stride (shorts): 144 B rows

// packed-weight layout (shorts): B-fragment order [kstep][ntile][lane][8]
#define P_E1 0        // w_e1: 5 ksteps (K=160 permuted: 0..127 h, 128..143 ea, 144 radial)
#define P_E2 10240    // w_e2: 2 ksteps
#define P_C1 14336    // w_c1: 2 ksteps
#define P_F1 18432    // w_f1: 4 ksteps (K=128)
#define P_F2 26624    // w_f2: 2 ksteps
#define PK_TOTAL 30720

// d_ws byte offsets
#define WS_CNT   0            // int[NN]      histogram
#define WS_OFF   200704       // int[NN+1]    CSR offsets
#define WS_CUR   401408       // int[NN]      scatter cursors
#define WS_EIDS  602112       // int[EE]      row-sorted edge ids
#define WS_PK    4602112      // short[PK_TOTAL] packed bf16 weights

typedef __attribute__((ext_vector_type(8))) short short8;
typedef __attribute__((ext_vector_type(4))) float f32x4;

__device__ __forceinline__ float fast_rcp(float v) { return __builtin_amdgcn_rcpf(v); }
__device__ __forceinline__ float silu_f(float v) { return v * fast_rcp(1.0f + __expf(-v)); }
__device__ __forceinline__ float ssgn_f(float v) { return v * fast_rcp(1.0f + fabsf(v)); }

__device__ __forceinline__ short f2bf(float f) {
    __hip_bfloat16 h = __float2bfloat16(f);
    return *reinterpret_cast<short*>(&h);
}
__device__ __forceinline__ float bf2f(short s) {
    union { unsigned u; float f; } c; c.u = ((unsigned)(unsigned short)s) << 16; return c.f;
}
__device__ __forceinline__ short8 pack8(float4 a, float4 b) {
    short8 r;
    r[0] = f2bf(a.x); r[1] = f2bf(a.y); r[2] = f2bf(a.z); r[3] = f2bf(a.w);
    r[4] = f2bf(b.x); r[5] = f2bf(b.y); r[6] = f2bf(b.z); r[7] = f2bf(b.w);
    return r;
}

// ---------------------------------------------------------------------------
// Counting sort of edges by destination row (deterministic per call)
// ---------------------------------------------------------------------------
__global__ void hist_kernel(const int* __restrict__ ei, int* __restrict__ cnt_i) {
    int e = blockIdx.x * 256 + threadIdx.x;
    if (e < EE) atomicAdd(&cnt_i[ei[e]], 1);
}

__global__ void scan_kernel(const int* __restrict__ cnt_i,
                            int* __restrict__ off, int* __restrict__ cur) {
    __shared__ int part[1024];
    const int t = threadIdx.x;
    const int CH = (NN + 1023) / 1024;   // 49
    int base = t * CH;
    int s = 0;
    for (int j = 0; j < CH; j++) { int idx = base + j; if (idx < NN) s += cnt_i[idx]; }
    part[t] = s;
    __syncthreads();
    for (int d = 1; d < 1024; d <<= 1) {
        int v = (t >= d) ? part[t - d] : 0;
        __syncthreads();
        part[t] += v;
        __syncthreads();
    }
    int excl = (t == 0) ? 0 : part[t - 1];
    for (int j = 0; j < CH; j++) {
        int idx = base + j;
        if (idx < NN) { off[idx] = excl; cur[idx] = excl; excl += cnt_i[idx]; }
    }
    if (t == 1023) off[NN] = part[1023];
}

__global__ void scatter_kernel(const int* __restrict__ ei,
                               int* __restrict__ cur, int* __restrict__ eids) {
    int e = blockIdx.x * 256 + threadIdx.x;
    if (e < EE) {
        int p = atomicAdd(&cur[ei[e]], 1);
        eids[p] = e;
    }
}

// ---------------------------------------------------------------------------
// Pack weights into MFMA B-fragment order: frag(s,n) lane l short j holds
// B[k = s*32 + (l>>4)*8 + j][col = n*16 + (l&15)], bf16, zero-padded K.
// mats: 0=w_e1 (K=160 permuted), 1=w_e2, 2=w_c1, 3=w_f1 (K=128), 4=w_f2
// ---------------------------------------------------------------------------
__global__ void pack_weights(const float* __restrict__ w_e1,
                             const float* __restrict__ w_e2,
                             const float* __restrict__ w_c1,
                             const float* __restrict__ w_f1,
                             const float* __restrict__ w_f2,
                             short* __restrict__ pk)
{
    int g = blockIdx.x * 256 + threadIdx.x;
    const int G_E1 = 5 * 4 * 64, G_E2 = 2 * 4 * 64, G_C1 = 2 * 4 * 64;
    const int G_F1 = 4 * 4 * 64, G_F2 = 2 * 4 * 64;
    if (g >= G_E1 + G_E2 + G_C1 + G_F1 + G_F2) return;
    const float* W; int loc; int mat;
    if (g < G_E1)                        { W = w_e1; loc = g;                         mat = 0; }
    else if (g < G_E1+G_E2)              { W = w_e2; loc = g - G_E1;                  mat = 1; }
    else if (g < G_E1+G_E2+G_C1)         { W = w_c1; loc = g - G_E1 - G_E2;           mat = 2; }
    else if (g < G_E1+G_E2+G_C1+G_F1)    { W = w_f1; loc = g - G_E1 - G_E2 - G_C1;    mat = 3; }
    else                                 { W = w_f2; loc = g - G_E1-G_E2-G_C1-G_F1;   mat = 4; }
    int l = loc & 63, n = (loc >> 6) & 3, s = loc >> 8;
    short8 out;
    #pragma unroll
    for (int j = 0; j < 8; j++) {
        int kp = s * 32 + ((l >> 4) * 8) + j;
        int ko; bool valid;
        if (mat == 0) {
            if (kp < 128)      { ko = kp;     valid = true; }
            else if (kp < 144) { ko = kp + 1; valid = true; }   // ea rows (orig 129..144)
            else if (kp == 144){ ko = 128;    valid = true; }   // radial row
            else               { ko = 0;      valid = false; }
        } else if (mat == 3) { ko = kp; valid = kp < 128; }
        else                 { ko = kp; valid = kp < 64; }
        float v = valid ? W[ko * 64 + (n * 16 + (l & 15))] : 0.0f;
        out[j] = f2bf(v);
    }
    *reinterpret_cast<short8*>(pk + (size_t)g * 8) = out;
}

// ---------------------------------------------------------------------------
// Edge kernel (MFMA, row-sorted, run-merged scatter, 40KB LDS -> 4 blocks/CU)
// ---------------------------------------------------------------------------
__global__ __launch_bounds__(256, 4) void edge_kernel(
    const float* __restrict__ h, const float* __restrict__ x,
    const int* __restrict__ ei, const float* __restrict__ ea,
    const int* __restrict__ eids,
    const float* __restrict__ b_e1, const float* __restrict__ b_e2,
    const float* __restrict__ b_c1, const float* __restrict__ w_c2,
    const short* __restrict__ pk,
    const float* __restrict__ sm_p, const float* __restrict__ om_p,
    float* __restrict__ agg, float* __restrict__ xagg)
{
    __shared__ short smem[4][64 * MSTR];   // 9216 B / wave
    __shared__ float aux_a[4][256];        // 1024 B / wave (phi bcast, then swv)
    const int wid  = threadIdx.x >> 6;
    const int lane = threadIdx.x & 63;
    short* sm  = smem[wid];
    float* aux = aux_a[wid];

    // bijective XCD swizzle (nwg = 7813, m204 formula)
    const int nwg = gridDim.x;
    const int q = nwg >> 3, r_ = nwg & 7;
    const int xcd = blockIdx.x & 7, kk = blockIdx.x >> 3;
    const int bswz = (xcd < r_ ? xcd * (q + 1) : r_ * (q + 1) + (xcd - r_) * q) + kk;

    const int WPB = EE / 64;
    const int gw = bswz * 4 + wid;
    if (gw >= NB * WPB) return;            // no barriers anywhere: safe
    const int b  = gw / WPB;
    const int i0 = (gw - b * WPB) * 64;    // sorted position base

    const int l15 = lane & 15;
    const int gq  = lane >> 4;
    const int kg  = gq * 8;

    const int eid = eids[i0 + lane];       // coalesced
    const int row = ei[eid];               // gather 4B
    const int col = ei[EE + eid];

    const float4 xr = *reinterpret_cast<const float4*>(x + ((size_t)b * NN + row) * 4);
    const float4 xc = *reinterpret_cast<const float4*>(x + ((size_t)b * NN + col) * 4);
    const float d0 = xr.x - xc.x, d1 = xr.y - xc.y, d2 = xr.z - xc.z, d3 = xr.w - xc.w;
    const float radial = d1 * d1 + d2 * d2 + d3 * d3 - d0 * d0;

    // per-lane indices / radial for the 4 M-tiles (cross-lane, no LDS space)
    int rowi[4], coli[4], eidm[4];
    float radm[4];
    #pragma unroll
    for (int m = 0; m < 4; m++) {
        int src = m * 16 + l15;
        rowi[m] = __shfl(row, src);
        coli[m] = __shfl(col, src);
        eidm[m] = __shfl(eid, src);
        radm[m] = __shfl(radial, src);
    }
    const float* hb = h + (size_t)b * NN * 64;

    // ---- GEMM1: m_in[64x160] @ w_e1 -> acc ----
    f32x4 acc[4][4];
    #pragma unroll
    for (int n = 0; n < 4; n++) {
        float bias = b_e1[n * 16 + l15];
        #pragma unroll
        for (int m = 0; m < 4; m++) acc[m][n] = f32x4{bias, bias, bias, bias};
    }
    const short8* pke1 = reinterpret_cast<const short8*>(pk + P_E1);
    #pragma unroll
    for (int s = 0; s < 5; s++) {
        short8 afr[4];
        if (s < 4) {
            #pragma unroll
            for (int m = 0; m < 4; m++) {
                int r = (s < 2) ? rowi[m] : coli[m];
                const float* src = hb + (size_t)r * 64 + (s & 1) * 32 + kg;
                float4 lo = *reinterpret_cast<const float4*>(src);
                float4 hi = *reinterpret_cast<const float4*>(src + 4);
                afr[m] = pack8(lo, hi);
            }
        } else {
            // tail fragment built directly: g0 -> ea[0..7], g1 -> ea[8..15],
            // g2 -> {radial,0...}, g3 -> 0   (matches packed permutation)
            #pragma unroll
            for (int m = 0; m < 4; m++) {
                short8 v = short8{0, 0, 0, 0, 0, 0, 0, 0};
                if (gq < 2) {
                    const float* src = ea + ((size_t)b * EE + eidm[m]) * 16 + gq * 8;
                    float4 lo = *reinterpret_cast<const float4*>(src);
                    float4 hi = *reinterpret_cast<const float4*>(src + 4);
                    v = pack8(lo, hi);
                } else if (gq == 2) {
                    v[0] = f2bf(radm[m]);
                }
                afr[m] = v;
            }
        }
        #pragma unroll
        for (int n = 0; n < 4; n++) {
            short8 bfr = pke1[(s * 4 + n) * 64 + lane];
            #pragma unroll
            for (int m = 0; m < 4; m++)
                acc[m][n] = __builtin_amdgcn_mfma_f32_16x16x32_bf16(afr[m], bfr, acc[m][n], 0, 0, 0);
        }
    }

    // ---- t1 = silu(acc) -> LDS ----
    #pragma unroll
    for (int m = 0; m < 4; m++)
        #pragma unroll
        for (int n = 0; n < 4; n++)
            #pragma unroll
            for (int r = 0; r < 4; r++)
                sm[(m * 16 + gq * 4 + r) * MSTR + n * 16 + l15] = f2bf(silu_f(acc[m][n][r]));
    asm volatile("s_waitcnt lgkmcnt(0)" ::: "memory");

    // ---- GEMM2: t1 @ w_e2 ----
    f32x4 acc2[4][4];
    #pragma unroll
    for (int n = 0; n < 4; n++) {
        float bias = b_e2[n * 16 + l15];
        #pragma unroll
        for (int m = 0; m < 4; m++) acc2[m][n] = f32x4{bias, bias, bias, bias};
    }
    const short8* pke2 = reinterpret_cast<const short8*>(pk + P_E2);
    #pragma unroll
    for (int s = 0; s < 2; s++) {
        short8 afr[4];
        #pragma unroll
        for (int m = 0; m < 4; m++)
            afr[m] = *reinterpret_cast<const short8*>(sm + (m * 16 + l15) * MSTR + s * 32 + kg);
        #pragma unroll
        for (int n = 0; n < 4; n++) {
            short8 bfr = pke2[(s * 4 + n) * 64 + lane];
            #pragma unroll
            for (int m = 0; m < 4; m++)
                acc2[m][n] = __builtin_amdgcn_mfma_f32_16x16x32_bf16(afr[m], bfr, acc2[m][n], 0, 0, 0);
        }
    }
    asm volatile("s_waitcnt lgkmcnt(0)" ::: "memory");

    // ---- m = softsign(acc2) -> LDS (overwrites t1) ----
    #pragma unroll
    for (int m = 0; m < 4; m++)
        #pragma unroll
        for (int n = 0; n < 4; n++)
            #pragma unroll
            for (int r = 0; r < 4; r++)
                sm[(m * 16 + gq * 4 + r) * MSTR + n * 16 + l15] = f2bf(ssgn_f(acc2[m][n][r]));
    asm volatile("s_waitcnt lgkmcnt(0)" ::: "memory");

    // ---- GEMM3: m @ w_c1 ; phi = silu(.) @ w_c2 ----
    f32x4 acc3[4][4];
    #pragma unroll
    for (int n = 0; n < 4; n++) {
        float bias = b_c1[n * 16 + l15];
        #pragma unroll
        for (int m = 0; m < 4; m++) acc3[m][n] = f32x4{bias, bias, bias, bias};
    }
    const short8* pkc1 = reinterpret_cast<const short8*>(pk + P_C1);
    #pragma unroll
    for (int s = 0; s < 2; s++) {
        short8 afr[4];
        #pragma unroll
        for (int m = 0; m < 4; m++)
            afr[m] = *reinterpret_cast<const short8*>(sm + (m * 16 + l15) * MSTR + s * 32 + kg);
        #pragma unroll
        for (int n = 0; n < 4; n++) {
            short8 bfr = pkc1[(s * 4 + n) * 64 + lane];
            #pragma unroll
            for (int m = 0; m < 4; m++)
                acc3[m][n] = __builtin_amdgcn_mfma_f32_16x16x32_bf16(afr[m], bfr, acc3[m][n], 0, 0, 0);
        }
    }
    float wc2v[4];
    #pragma unroll
    for (int n = 0; n < 4; n++) wc2v[n] = w_c2[n * 16 + l15];
    #pragma unroll
    for (int m = 0; m < 4; m++)
        #pragma unroll
        for (int r = 0; r < 4; r++) {
            float v = 0.0f;
            #pragma unroll
            for (int n = 0; n < 4; n++) v = fmaf(silu_f(acc3[m][n][r]), wc2v[n], v);
            v += __shfl_xor(v, 1); v += __shfl_xor(v, 2);
            v += __shfl_xor(v, 4); v += __shfl_xor(v, 8);
            if (l15 == 0) aux[m * 16 + gq * 4 + r] = v;
        }
    asm volatile("s_waitcnt lgkmcnt(0)" ::: "memory");
    const float phiv = aux[lane];
    asm volatile("s_waitcnt lgkmcnt(0)" ::: "memory");

    // ---- weighted coordinates into aux (overwrites phi region after read) ----
    const float smv = sm_p[0], omv = om_p[0];
    aux[lane * 4 + 0] = (smv * xr.x + omv * xc.x) * phiv;
    aux[lane * 4 + 1] = (smv * xr.y + omv * xc.y) * phiv;
    aux[lane * 4 + 2] = (smv * xr.z + omv * xc.z) * phiv;
    aux[lane * 4 + 3] = (smv * xr.w + omv * xc.w) * phiv;
    asm volatile("s_waitcnt lgkmcnt(0)" ::: "memory");

    // ---- combined run-merged scatter (agg: lane=feature; xagg: lanes 0-3) ----
    float* aggb = agg + (size_t)b * NN * 64;
    float* xb   = xagg + (size_t)b * NN * 4;
    float mv = 0.0f, xv = 0.0f;
    #pragma unroll
    for (int e = 0; e < 64; e++) {
        mv += bf2f(sm[e * MSTR + lane]);
        float t = aux[e * 4 + (lane & 3)];
        xv += (lane < 4) ? t : 0.0f;
        int re = __shfl(row, e);
        int rn = (e < 63) ? __shfl(row, e + 1) : -1;
        if (re != rn) {
            atomicAdd(aggb + (size_t)re * 64 + lane, mv);
            if (lane < 4) atomicAdd(xb + (size_t)re * 4 + lane, xv);
            mv = 0.0f; xv = 0.0f;
        }
    }
}

// ---------------------------------------------------------------------------
// Node kernel (MFMA): h_upd = softsign(silu([h,agg]@w_f1+b_f1)@w_f2+b_f2)
// ---------------------------------------------------------------------------
__global__ __launch_bounds__(256, 4) void node_kernel(
    const float* __restrict__ h, const float* __restrict__ x,
    const float* __restrict__ b_f1, const float* __restrict__ b_f2,
    const short* __restrict__ pk,
    const int* __restrict__ off,
    float* out_h,   // also agg [B,N,64]
    float* out_x)   // also xagg [B,N,4]
{
    __shared__ short smem[4][64 * MSTR];
    const int wid  = threadIdx.x >> 6;
    const int lane = threadIdx.x & 63;
    short* sm = smem[wid];

    const int WN = (NN + 63) / 64;   // 782
    const int gw = blockIdx.x * 4 + wid;
    if (gw >= NB * WN) return;
    const int b  = gw / WN;
    const int n0 = (gw - b * WN) * 64;

    const int l15 = lane & 15;
    const int gq  = lane >> 4;
    const int kg  = gq * 8;

    const float* hb   = h + (size_t)b * NN * 64;
    const float* aggb = out_h + (size_t)b * NN * 64;

    // ---- GEMM1: [h,agg] (K=128) @ w_f1 ----
    f32x4 acc[4][4];
    #pragma unroll
    for (int n = 0; n < 4; n++) {
        float bias = b_f1[n * 16 + l15];
        #pragma unroll
        for (int m = 0; m < 4; m++) acc[m][n] = f32x4{bias, bias, bias, bias};
    }
    const short8* pkf1 = reinterpret_cast<const short8*>(pk + P_F1);
    #pragma unroll
    for (int s = 0; s < 4; s++) {
        short8 afr[4];
        #pragma unroll
        for (int m = 0; m < 4; m++) {
            int nd = n0 + m * 16 + l15;
            if (nd >= NN) nd = NN - 1;               // clamp; store is guarded
            const float* base = (s < 2 ? hb : aggb) + (size_t)nd * 64 + (s & 1) * 32 + kg;
            float4 lo = *reinterpret_cast<const float4*>(base);
            float4 hi = *reinterpret_cast<const float4*>(base + 4);
            afr[m] = pack8(lo, hi);
        }
        #pragma unroll
        for (int n = 0; n < 4; n++) {
            short8 bfr = pkf1[(s * 4 + n) * 64 + lane];
            #pragma unroll
            for (int m = 0; m < 4; m++)
                acc[m][n] = __builtin_amdgcn_mfma_f32_16x16x32_bf16(afr[m], bfr, acc[m][n], 0, 0, 0);
        }
    }

    // ---- t1 = silu -> LDS ----
    #pragma unroll
    for (int m = 0; m < 4; m++)
        #pragma unroll
        for (int n = 0; n < 4; n++)
            #pragma unroll
            for (int r = 0; r < 4; r++)
                sm[(m * 16 + gq * 4 + r) * MSTR + n * 16 + l15] = f2bf(silu_f(acc[m][n][r]));
    asm volatile("s_waitcnt lgkmcnt(0)" ::: "memory");

    // ---- GEMM2: t1 @ w_f2 ----
    f32x4 acc2[4][4];
    #pragma unroll
    for (int n = 0; n < 4; n++) {
        float bias = b_f2[n * 16 + l15];
        #pragma unroll
        for (int m = 0; m < 4; m++) acc2[m][n] = f32x4{bias, bias, bias, bias};
    }
    const short8* pkf2 = reinterpret_cast<const short8*>(pk + P_F2);
    #pragma unroll
    for (int s = 0; s < 2; s++) {
        short8 afr[4];
        #pragma unroll
        for (int m = 0; m < 4; m++)
            afr[m] = *reinterpret_cast<const short8*>(sm + (m * 16 + l15) * MSTR + s * 32 + kg);
        #pragma unroll
        for (int n = 0; n < 4; n++) {
            short8 bfr = pkf2[(s * 4 + n) * 64 + lane];
            #pragma unroll
            for (int m = 0; m < 4; m++)
                acc2[m][n] = __builtin_amdgcn_mfma_f32_16x16x32_bf16(afr[m], bfr, acc2[m][n], 0, 0, 0);
        }
    }

    // ---- softsign + direct store (f32, 64B segments) ----
    float* ohb = out_h + (size_t)b * NN * 64;
    #pragma unroll
    for (int m = 0; m < 4; m++)
        #pragma unroll
        for (int r = 0; r < 4; r++) {
            int nd = n0 + m * 16 + gq * 4 + r;
            if (nd < NN) {
                #pragma unroll
                for (int n = 0; n < 4; n++)
                    ohb[(size_t)nd * 64 + n * 16 + l15] = ssgn_f(acc2[m][n][r]);
            }
        }

    // ---- x update ----
    const int node = n0 + lane;
    if (node < NN) {
        int c_i = off[node + 1] - off[node];
        float c = (float)(c_i < 1 ? 1 : c_i);
        float invc = fast_rcp(c);
        const float4 xv = *reinterpret_cast<const float4*>(x + ((size_t)b * NN + node) * 4);
        float* xop = out_x + ((size_t)b * NN + node) * 4;
        float4 xa = *reinterpret_cast<float4*>(xop);
        float4 r;
        r.x = xv.x + xa.x * invc;
        r.y = xv.y + xa.y * invc;
        r.z = xv.z + xa.z * invc;
        r.w = xv.w + xa.w * invc;
        *reinterpret_cast<float4*>(xop) = r;
    }
}

// ---------------------------------------------------------------------------
extern "C" void kernel_launch(void* const* d_in, const int* in_sizes, int n_in,
                              void* d_out, int out_size, void* d_ws, size_t ws_size,
                              hipStream_t stream) {
    const float* h    = (const float*)d_in[0];
    const float* x    = (const float*)d_in[1];
    const int*   ei   = (const int*)d_in[2];
    const float* ea   = (const float*)d_in[3];
    const float* w_e1 = (const float*)d_in[4];
    const float* b_e1 = (const float*)d_in[5];
    const float* w_e2 = (const float*)d_in[6];
    const float* b_e2 = (const float*)d_in[7];
    const float* w_f1 = (const float*)d_in[8];
    const float* b_f1 = (const float*)d_in[9];
    const float* w_f2 = (const float*)d_in[10];
    const float* b_f2 = (const float*)d_in[11];
    const float* w_c1 = (const float*)d_in[12];
    const float* b_c1 = (const float*)d_in[13];
    const float* w_c2 = (const float*)d_in[14];
    const float* smp  = (const float*)d_in[15];
    const float* omp  = (const float*)d_in[16];

    float* out   = (float*)d_out;
    float* agg   = out;                               // [B,N,64] scratch -> h_updated
    float* out_x = out + (size_t)NB * NN * 64;        // [B,N,4]  scratch -> x_updated

    char* ws = (char*)d_ws;
    int*   cnt_i = (int*)(ws + WS_CNT);
    int*   off   = (int*)(ws + WS_OFF);
    int*   cur   = (int*)(ws + WS_CUR);
    int*   eids  = (int*)(ws + WS_EIDS);
    short* pk    = (short*)(ws + WS_PK);

    hipMemsetAsync(d_out, 0, (size_t)out_size * sizeof(float), stream);
    hipMemsetAsync(cnt_i, 0, (size_t)NN * sizeof(int), stream);

    pack_weights<<<15, 256, 0, stream>>>(w_e1, w_e2, w_c1, w_f1, w_f2, pk);

    const int eb = (EE + 255) / 256;
    hist_kernel<<<eb, 256, 0, stream>>>(ei, cnt_i);
    scan_kernel<<<1, 1024, 0, stream>>>(cnt_i, off, cur);
    scatter_kernel<<<eb, 256, 0, stream>>>(ei, cur, eids);

    const int edge_waves = NB * (EE / 64);            // 31250
    const int edge_blocks = (edge_waves + 3) / 4;     // 7813
    edge_kernel<<<edge_blocks, 256, 0, stream>>>(
        h, x, ei, ea, eids, b_e1, b_e2, b_c1, w_c2, pk,
        smp, omp, agg, out_x);

    const int node_waves = NB * ((NN + 63) / 64);     // 1564
    const int node_blocks = (node_waves + 3) / 4;     // 391
    node_kernel<<<node_blocks, 256, 0, stream>>>(
        h, x, b_f1, b_f2, pk, off, agg, out_x);
}

// Round 5
// 570.298 us; speedup vs baseline: 3.4696x; 1.0095x over previous
//
#include <hip/hip_runtime.h>
#include <hip/hip_bf16.h>
#include <cstdint>
#include <cstddef>

#define NN 50000     // nodes
#define EE 1000000   // edges
#define NB 2         // batch

#define MSTR 72      // activation tile stride (shorts): 144 B rows

// packed-weight layout (shorts): B-fragment order [kstep][ntile][lane][8]
#define P_E1 0        // w_e1: 5 ksteps (K=160 permuted: 0..127 h, 128..143 ea, 144 radial)
#define P_E2 10240    // w_e2: 2 ksteps
#define P_C1 14336    // w_c1: 2 ksteps
#define P_F1 18432    // w_f1: 4 ksteps (K=128)
#define P_F2 26624    // w_f2: 2 ksteps
#define PK_TOTAL 30720

// d_ws byte offsets
#define WS_CNT   0            // int[NN]      histogram
#define WS_OFF   200704       // int[NN+1]    CSR offsets
#define WS_CUR   401408       // int[NN]      scatter cursors
#define WS_EIDS  602112       // int[EE]      row-sorted edge ids
#define WS_PK    4602112      // short[PK_TOTAL] packed bf16 weights
#define WS_HB    4663552      // short[NB*NN*64] pre-converted bf16 h (12.8 MB)
// total ~17.5 MB

typedef __attribute__((ext_vector_type(8))) short short8;
typedef __attribute__((ext_vector_type(4))) float f32x4;

__device__ __forceinline__ float fast_rcp(float v) { return __builtin_amdgcn_rcpf(v); }
__device__ __forceinline__ float silu_f(float v) { return v * fast_rcp(1.0f + __expf(-v)); }
__device__ __forceinline__ float ssgn_f(float v) { return v * fast_rcp(1.0f + fabsf(v)); }

__device__ __forceinline__ short f2bf(float f) {
    __hip_bfloat16 h = __float2bfloat16(f);
    return *reinterpret_cast<short*>(&h);
}
__device__ __forceinline__ float bf2f(short s) {
    union { unsigned u; float f; } c; c.u = ((unsigned)(unsigned short)s) << 16; return c.f;
}
__device__ __forceinline__ short8 pack8(float4 a, float4 b) {
    short8 r;
    r[0] = f2bf(a.x); r[1] = f2bf(a.y); r[2] = f2bf(a.z); r[3] = f2bf(a.w);
    r[4] = f2bf(b.x); r[5] = f2bf(b.y); r[6] = f2bf(b.z); r[7] = f2bf(b.w);
    return r;
}

// ---------------------------------------------------------------------------
// Pre-convert h -> bf16 (same RNE rounding the edge kernel already applied)
// ---------------------------------------------------------------------------
__global__ void conv_h(const float* __restrict__ h, short* __restrict__ hb16) {
    size_t i = ((size_t)blockIdx.x * 256 + threadIdx.x) * 8;   // 6.4M elems, grid exact
    float4 lo = *reinterpret_cast<const float4*>(h + i);
    float4 hi = *reinterpret_cast<const float4*>(h + i + 4);
    *reinterpret_cast<short8*>(hb16 + i) = pack8(lo, hi);
}

// ---------------------------------------------------------------------------
// Counting sort of edges by destination row (deterministic per call)
// ---------------------------------------------------------------------------
__global__ void hist_kernel(const int* __restrict__ ei, int* __restrict__ cnt_i) {
    int e = blockIdx.x * 256 + threadIdx.x;
    if (e < EE) atomicAdd(&cnt_i[ei[e]], 1);
}

__global__ void scan_kernel(const int* __restrict__ cnt_i,
                            int* __restrict__ off, int* __restrict__ cur) {
    __shared__ int part[1024];
    const int t = threadIdx.x;
    const int CH = (NN + 1023) / 1024;   // 49
    int base = t * CH;
    int s = 0;
    for (int j = 0; j < CH; j++) { int idx = base + j; if (idx < NN) s += cnt_i[idx]; }
    part[t] = s;
    __syncthreads();
    for (int d = 1; d < 1024; d <<= 1) {
        int v = (t >= d) ? part[t - d] : 0;
        __syncthreads();
        part[t] += v;
        __syncthreads();
    }
    int excl = (t == 0) ? 0 : part[t - 1];
    for (int j = 0; j < CH; j++) {
        int idx = base + j;
        if (idx < NN) { off[idx] = excl; cur[idx] = excl; excl += cnt_i[idx]; }
    }
    if (t == 1023) off[NN] = part[1023];
}

__global__ void scatter_kernel(const int* __restrict__ ei,
                               int* __restrict__ cur, int* __restrict__ eids) {
    int e = blockIdx.x * 256 + threadIdx.x;
    if (e < EE) {
        int p = atomicAdd(&cur[ei[e]], 1);
        eids[p] = e;
    }
}

// ---------------------------------------------------------------------------
// Pack weights into MFMA B-fragment order: frag(s,n) lane l short j holds
// B[k = s*32 + (l>>4)*8 + j][col = n*16 + (l&15)], bf16, zero-padded K.
// mats: 0=w_e1 (K=160 permuted), 1=w_e2, 2=w_c1, 3=w_f1 (K=128), 4=w_f2
// ---------------------------------------------------------------------------
__global__ void pack_weights(const float* __restrict__ w_e1,
                             const float* __restrict__ w_e2,
                             const float* __restrict__ w_c1,
                             const float* __restrict__ w_f1,
                             const float* __restrict__ w_f2,
                             short* __restrict__ pk)
{
    int g = blockIdx.x * 256 + threadIdx.x;
    const int G_E1 = 5 * 4 * 64, G_E2 = 2 * 4 * 64, G_C1 = 2 * 4 * 64;
    const int G_F1 = 4 * 4 * 64, G_F2 = 2 * 4 * 64;
    if (g >= G_E1 + G_E2 + G_C1 + G_F1 + G_F2) return;
    const float* W; int loc; int mat;
    if (g < G_E1)                        { W = w_e1; loc = g;                         mat = 0; }
    else if (g < G_E1+G_E2)              { W = w_e2; loc = g - G_E1;                  mat = 1; }
    else if (g < G_E1+G_E2+G_C1)         { W = w_c1; loc = g - G_E1 - G_E2;           mat = 2; }
    else if (g < G_E1+G_E2+G_C1+G_F1)    { W = w_f1; loc = g - G_E1 - G_E2 - G_C1;    mat = 3; }
    else                                 { W = w_f2; loc = g - G_E1-G_E2-G_C1-G_F1;   mat = 4; }
    int l = loc & 63, n = (loc >> 6) & 3, s = loc >> 8;
    short8 out;
    #pragma unroll
    for (int j = 0; j < 8; j++) {
        int kp = s * 32 + ((l >> 4) * 8) + j;
        int ko; bool valid;
        if (mat == 0) {
            if (kp < 128)      { ko = kp;     valid = true; }
            else if (kp < 144) { ko = kp + 1; valid = true; }   // ea rows (orig 129..144)
            else if (kp == 144){ ko = 128;    valid = true; }   // radial row
            else               { ko = 0;      valid = false; }
        } else if (mat == 3) { ko = kp; valid = kp < 128; }
        else                 { ko = kp; valid = kp < 64; }
        float v = valid ? W[ko * 64 + (n * 16 + (l & 15))] : 0.0f;
        out[j] = f2bf(v);
    }
    *reinterpret_cast<short8*>(pk + (size_t)g * 8) = out;
}

// ---------------------------------------------------------------------------
// Edge kernel (MFMA, row-sorted, ballot run-merged scatter, bf16 h gathers)
// ---------------------------------------------------------------------------
__global__ __launch_bounds__(256, 4) void edge_kernel(
    const short* __restrict__ hb16, const float* __restrict__ x,
    const int* __restrict__ ei, const float* __restrict__ ea,
    const int* __restrict__ eids,
    const float* __restrict__ b_e1, const float* __restrict__ b_e2,
    const float* __restrict__ b_c1, const float* __restrict__ w_c2,
    const short* __restrict__ pk,
    const float* __restrict__ sm_p, const float* __restrict__ om_p,
    float* __restrict__ agg, float* __restrict__ xagg)
{
    __shared__ short smem[4][64 * MSTR];   // 9216 B / wave
    __shared__ float aux_a[4][256];        // 1024 B / wave (phi bcast, then swv)
    const int wid  = threadIdx.x >> 6;
    const int lane = threadIdx.x & 63;
    short* sm  = smem[wid];
    float* aux = aux_a[wid];

    // bijective XCD swizzle (nwg = 7813, m204 formula)
    const int nwg = gridDim.x;
    const int q = nwg >> 3, r_ = nwg & 7;
    const int xcd = blockIdx.x & 7, kk = blockIdx.x >> 3;
    const int bswz = (xcd < r_ ? xcd * (q + 1) : r_ * (q + 1) + (xcd - r_) * q) + kk;

    const int WPB = EE / 64;
    const int gw = bswz * 4 + wid;
    if (gw >= NB * WPB) return;            // no barriers anywhere: safe
    const int b  = gw / WPB;
    const int i0 = (gw - b * WPB) * 64;    // sorted position base

    const int l15 = lane & 15;
    const int gq  = lane >> 4;
    const int kg  = gq * 8;

    const int eid = eids[i0 + lane];       // coalesced
    const int row = ei[eid];               // gather 4B (ei is L2/L3-resident)
    const int col = ei[EE + eid];

    const float4 xr = *reinterpret_cast<const float4*>(x + ((size_t)b * NN + row) * 4);
    const float4 xc = *reinterpret_cast<const float4*>(x + ((size_t)b * NN + col) * 4);
    const float d0 = xr.x - xc.x, d1 = xr.y - xc.y, d2 = xr.z - xc.z, d3 = xr.w - xc.w;
    const float radial = d1 * d1 + d2 * d2 + d3 * d3 - d0 * d0;

    // per-lane indices / radial for the 4 M-tiles (cross-lane, no LDS space)
    int rowi[4], coli[4], eidm[4];
    float radm[4];
    #pragma unroll
    for (int m = 0; m < 4; m++) {
        int src = m * 16 + l15;
        rowi[m] = __shfl(row, src);
        coli[m] = __shfl(col, src);
        eidm[m] = __shfl(eid, src);
        radm[m] = __shfl(radial, src);
    }
    const short* hbb = hb16 + (size_t)b * NN * 64;

    // ---- GEMM1: m_in[64x160] @ w_e1 -> acc ----
    f32x4 acc[4][4];
    #pragma unroll
    for (int n = 0; n < 4; n++) {
        float bias = b_e1[n * 16 + l15];
        #pragma unroll
        for (int m = 0; m < 4; m++) acc[m][n] = f32x4{bias, bias, bias, bias};
    }
    const short8* pke1 = reinterpret_cast<const short8*>(pk + P_E1);
    #pragma unroll
    for (int s = 0; s < 5; s++) {
        short8 afr[4];
        if (s < 4) {
            #pragma unroll
            for (int m = 0; m < 4; m++) {
                int r = (s < 2) ? rowi[m] : coli[m];
                afr[m] = *reinterpret_cast<const short8*>(
                    hbb + (size_t)r * 64 + (s & 1) * 32 + kg);       // 16B bf16 load
            }
        } else {
            // tail fragment: g0 -> ea[0..7], g1 -> ea[8..15], g2 -> {radial,0..}, g3 -> 0
            #pragma unroll
            for (int m = 0; m < 4; m++) {
                short8 v = short8{0, 0, 0, 0, 0, 0, 0, 0};
                if (gq < 2) {
                    const float* src = ea + ((size_t)b * EE + eidm[m]) * 16 + gq * 8;
                    float4 lo = *reinterpret_cast<const float4*>(src);
                    float4 hi = *reinterpret_cast<const float4*>(src + 4);
                    v = pack8(lo, hi);
                } else if (gq == 2) {
                    v[0] = f2bf(radm[m]);
                }
                afr[m] = v;
            }
        }
        __builtin_amdgcn_s_setprio(1);
        #pragma unroll
        for (int n = 0; n < 4; n++) {
            short8 bfr = pke1[(s * 4 + n) * 64 + lane];
            #pragma unroll
            for (int m = 0; m < 4; m++)
                acc[m][n] = __builtin_amdgcn_mfma_f32_16x16x32_bf16(afr[m], bfr, acc[m][n], 0, 0, 0);
        }
        __builtin_amdgcn_s_setprio(0);
    }

    // ---- t1 = silu(acc) -> LDS ----
    #pragma unroll
    for (int m = 0; m < 4; m++)
        #pragma unroll
        for (int n = 0; n < 4; n++)
            #pragma unroll
            for (int r = 0; r < 4; r++)
                sm[(m * 16 + gq * 4 + r) * MSTR + n * 16 + l15] = f2bf(silu_f(acc[m][n][r]));
    asm volatile("s_waitcnt lgkmcnt(0)" ::: "memory");

    // ---- GEMM2: t1 @ w_e2 ----
    f32x4 acc2[4][4];
    #pragma unroll
    for (int n = 0; n < 4; n++) {
        float bias = b_e2[n * 16 + l15];
        #pragma unroll
        for (int m = 0; m < 4; m++) acc2[m][n] = f32x4{bias, bias, bias, bias};
    }
    const short8* pke2 = reinterpret_cast<const short8*>(pk + P_E2);
    #pragma unroll
    for (int s = 0; s < 2; s++) {
        short8 afr[4];
        #pragma unroll
        for (int m = 0; m < 4; m++)
            afr[m] = *reinterpret_cast<const short8*>(sm + (m * 16 + l15) * MSTR + s * 32 + kg);
        __builtin_amdgcn_s_setprio(1);
        #pragma unroll
        for (int n = 0; n < 4; n++) {
            short8 bfr = pke2[(s * 4 + n) * 64 + lane];
            #pragma unroll
            for (int m = 0; m < 4; m++)
                acc2[m][n] = __builtin_amdgcn_mfma_f32_16x16x32_bf16(afr[m], bfr, acc2[m][n], 0, 0, 0);
        }
        __builtin_amdgcn_s_setprio(0);
    }
    asm volatile("s_waitcnt lgkmcnt(0)" ::: "memory");

    // ---- m = softsign(acc2) -> LDS (overwrites t1) ----
    #pragma unroll
    for (int m = 0; m < 4; m++)
        #pragma unroll
        for (int n = 0; n < 4; n++)
            #pragma unroll
            for (int r = 0; r < 4; r++)
                sm[(m * 16 + gq * 4 + r) * MSTR + n * 16 + l15] = f2bf(ssgn_f(acc2[m][n][r]));
    asm volatile("s_waitcnt lgkmcnt(0)" ::: "memory");

    // ---- GEMM3: m @ w_c1 ; phi = silu(.) @ w_c2 ----
    f32x4 acc3[4][4];
    #pragma unroll
    for (int n = 0; n < 4; n++) {
        float bias = b_c1[n * 16 + l15];
        #pragma unroll
        for (int m = 0; m < 4; m++) acc3[m][n] = f32x4{bias, bias, bias, bias};
    }
    const short8* pkc1 = reinterpret_cast<const short8*>(pk + P_C1);
    #pragma unroll
    for (int s = 0; s < 2; s++) {
        short8 afr[4];
        #pragma unroll
        for (int m = 0; m < 4; m++)
            afr[m] = *reinterpret_cast<const short8*>(sm + (m * 16 + l15) * MSTR + s * 32 + kg);
        __builtin_amdgcn_s_setprio(1);
        #pragma unroll
        for (int n = 0; n < 4; n++) {
            short8 bfr = pkc1[(s * 4 + n) * 64 + lane];
            #pragma unroll
            for (int m = 0; m < 4; m++)
                acc3[m][n] = __builtin_amdgcn_mfma_f32_16x16x32_bf16(afr[m], bfr, acc3[m][n], 0, 0, 0);
        }
        __builtin_amdgcn_s_setprio(0);
    }
    float wc2v[4];
    #pragma unroll
    for (int n = 0; n < 4; n++) wc2v[n] = w_c2[n * 16 + l15];
    #pragma unroll
    for (int m = 0; m < 4; m++)
        #pragma unroll
        for (int r = 0; r < 4; r++) {
            float v = 0.0f;
            #pragma unroll
            for (int n = 0; n < 4; n++) v = fmaf(silu_f(acc3[m][n][r]), wc2v[n], v);
            v += __shfl_xor(v, 1); v += __shfl_xor(v, 2);
            v += __shfl_xor(v, 4); v += __shfl_xor(v, 8);
            if (l15 == 0) aux[m * 16 + gq * 4 + r] = v;
        }
    asm volatile("s_waitcnt lgkmcnt(0)" ::: "memory");
    const float phiv = aux[lane];
    asm volatile("s_waitcnt lgkmcnt(0)" ::: "memory");

    // ---- weighted coordinates into aux (overwrites phi region after read) ----
    const float smv = sm_p[0], omv = om_p[0];
    aux[lane * 4 + 0] = (smv * xr.x + omv * xc.x) * phiv;
    aux[lane * 4 + 1] = (smv * xr.y + omv * xc.y) * phiv;
    aux[lane * 4 + 2] = (smv * xr.z + omv * xc.z) * phiv;
    aux[lane * 4 + 3] = (smv * xr.w + omv * xc.w) * phiv;
    asm volatile("s_waitcnt lgkmcnt(0)" ::: "memory");

    // ---- ballot run-merged scatter (agg: lane=feature; xagg: lanes 0-3) ----
    int nrow = __shfl_down(row, 1);
    unsigned long long bmask = __ballot((lane == 63) || (row != nrow));  // wave-uniform
    float* aggb = agg + (size_t)b * NN * 64;
    float* xb   = xagg + (size_t)b * NN * 4;
    float mv = 0.0f, xv = 0.0f;
    #pragma unroll
    for (int e = 0; e < 64; e++) {
        mv += bf2f(sm[e * MSTR + lane]);
        float t = aux[e * 4 + (lane & 3)];
        xv += (lane < 4) ? t : 0.0f;
        if ((bmask >> e) & 1ull) {         // uniform scalar branch
            int re = __shfl(row, e);
            atomicAdd(aggb + (size_t)re * 64 + lane, mv);
            if (lane < 4) atomicAdd(xb + (size_t)re * 4 + lane, xv);
            mv = 0.0f; xv = 0.0f;
        }
    }
}

// ---------------------------------------------------------------------------
// Node kernel (MFMA): h_upd = softsign(silu([h,agg]@w_f1+b_f1)@w_f2+b_f2)
// ---------------------------------------------------------------------------
__global__ __launch_bounds__(256, 4) void node_kernel(
    const short* __restrict__ hb16, const float* __restrict__ x,
    const float* __restrict__ b_f1, const float* __restrict__ b_f2,
    const short* __restrict__ pk,
    const int* __restrict__ off,
    float* out_h,   // also agg [B,N,64]
    float* out_x)   // also xagg [B,N,4]
{
    __shared__ short smem[4][64 * MSTR];
    const int wid  = threadIdx.x >> 6;
    const int lane = threadIdx.x & 63;
    short* sm = smem[wid];

    const int WN = (NN + 63) / 64;   // 782
    const int gw = blockIdx.x * 4 + wid;
    if (gw >= NB * WN) return;
    const int b  = gw / WN;
    const int n0 = (gw - b * WN) * 64;

    const int l15 = lane & 15;
    const int gq  = lane >> 4;
    const int kg  = gq * 8;

    const short* hbb  = hb16 + (size_t)b * NN * 64;
    const float* aggb = out_h + (size_t)b * NN * 64;

    // ---- GEMM1: [h,agg] (K=128) @ w_f1 ----
    f32x4 acc[4][4];
    #pragma unroll
    for (int n = 0; n < 4; n++) {
        float bias = b_f1[n * 16 + l15];
        #pragma unroll
        for (int m = 0; m < 4; m++) acc[m][n] = f32x4{bias, bias, bias, bias};
    }
    const short8* pkf1 = reinterpret_cast<const short8*>(pk + P_F1);
    #pragma unroll
    for (int s = 0; s < 4; s++) {
        short8 afr[4];
        #pragma unroll
        for (int m = 0; m < 4; m++) {
            int nd = n0 + m * 16 + l15;
            if (nd >= NN) nd = NN - 1;               // clamp; store is guarded
            if (s < 2) {
                afr[m] = *reinterpret_cast<const short8*>(
                    hbb + (size_t)nd * 64 + s * 32 + kg);
            } else {
                const float* base = aggb + (size_t)nd * 64 + (s & 1) * 32 + kg;
                float4 lo = *reinterpret_cast<const float4*>(base);
                float4 hi = *reinterpret_cast<const float4*>(base + 4);
                afr[m] = pack8(lo, hi);
            }
        }
        __builtin_amdgcn_s_setprio(1);
        #pragma unroll
        for (int n = 0; n < 4; n++) {
            short8 bfr = pkf1[(s * 4 + n) * 64 + lane];
            #pragma unroll
            for (int m = 0; m < 4; m++)
                acc[m][n] = __builtin_amdgcn_mfma_f32_16x16x32_bf16(afr[m], bfr, acc[m][n], 0, 0, 0);
        }
        __builtin_amdgcn_s_setprio(0);
    }

    // ---- t1 = silu -> LDS ----
    #pragma unroll
    for (int m = 0; m < 4; m++)
        #pragma unroll
        for (int n = 0; n < 4; n++)
            #pragma unroll
            for (int r = 0; r < 4; r++)
                sm[(m * 16 + gq * 4 + r) * MSTR + n * 16 + l15] = f2bf(silu_f(acc[m][n][r]));
    asm volatile("s_waitcnt lgkmcnt(0)" ::: "memory");

    // ---- GEMM2: t1 @ w_f2 ----
    f32x4 acc2[4][4];
    #pragma unroll
    for (int n = 0; n < 4; n++) {
        float bias = b_f2[n * 16 + l15];
        #pragma unroll
        for (int m = 0; m < 4; m++) acc2[m][n] = f32x4{bias, bias, bias, bias};
    }
    const short8* pkf2 = reinterpret_cast<const short8*>(pk + P_F2);
    #pragma unroll
    for (int s = 0; s < 2; s++) {
        short8 afr[4];
        #pragma unroll
        for (int m = 0; m < 4; m++)
            afr[m] = *reinterpret_cast<const short8*>(sm + (m * 16 + l15) * MSTR + s * 32 + kg);
        __builtin_amdgcn_s_setprio(1);
        #pragma unroll
        for (int n = 0; n < 4; n++) {
            short8 bfr = pkf2[(s * 4 + n) * 64 + lane];
            #pragma unroll
            for (int m = 0; m < 4; m++)
                acc2[m][n] = __builtin_amdgcn_mfma_f32_16x16x32_bf16(afr[m], bfr, acc2[m][n], 0, 0, 0);
        }
        __builtin_amdgcn_s_setprio(0);
    }

    // ---- softsign + direct store (f32, 64B segments) ----
    float* ohb = out_h + (size_t)b * NN * 64;
    #pragma unroll
    for (int m = 0; m < 4; m++)
        #pragma unroll
        for (int r = 0; r < 4; r++) {
            int nd = n0 + m * 16 + gq * 4 + r;
            if (nd < NN) {
                #pragma unroll
                for (int n = 0; n < 4; n++)
                    ohb[(size_t)nd * 64 + n * 16 + l15] = ssgn_f(acc2[m][n][r]);
            }
        }

    // ---- x update ----
    const int node = n0 + lane;
    if (node < NN) {
        int c_i = off[node + 1] - off[node];
        float c = (float)(c_i < 1 ? 1 : c_i);
        float invc = fast_rcp(c);
        const float4 xv = *reinterpret_cast<const float4*>(x + ((size_t)b * NN + node) * 4);
        float* xop = out_x + ((size_t)b * NN + node) * 4;
        float4 xa = *reinterpret_cast<float4*>(xop);
        float4 r;
        r.x = xv.x + xa.x * invc;
        r.y = xv.y + xa.y * invc;
        r.z = xv.z + xa.z * invc;
        r.w = xv.w + xa.w * invc;
        *reinterpret_cast<float4*>(xop) = r;
    }
}

// ---------------------------------------------------------------------------
extern "C" void kernel_launch(void* const* d_in, const int* in_sizes, int n_in,
                              void* d_out, int out_size, void* d_ws, size_t ws_size,
                              hipStream_t stream) {
    const float* h    = (const float*)d_in[0];
    const float* x    = (const float*)d_in[1];
    const int*   ei   = (const int*)d_in[2];
    const float* ea   = (const float*)d_in[3];
    const float* w_e1 = (const float*)d_in[4];
    const float* b_e1 = (const float*)d_in[5];
    const float* w_e2 = (const float*)d_in[6];
    const float* b_e2 = (const float*)d_in[7];
    const float* w_f1 = (const float*)d_in[8];
    const float* b_f1 = (const float*)d_in[9];
    const float* w_f2 = (const float*)d_in[10];
    const float* b_f2 = (const float*)d_in[11];
    const float* w_c1 = (const float*)d_in[12];
    const float* b_c1 = (const float*)d_in[13];
    const float* w_c2 = (const float*)d_in[14];
    const float* smp  = (const float*)d_in[15];
    const float* omp  = (const float*)d_in[16];

    float* out   = (float*)d_out;
    float* agg   = out;                               // [B,N,64] scratch -> h_updated
    float* out_x = out + (size_t)NB * NN * 64;        // [B,N,4]  scratch -> x_updated

    char* ws = (char*)d_ws;
    int*   cnt_i = (int*)(ws + WS_CNT);
    int*   off   = (int*)(ws + WS_OFF);
    int*   cur   = (int*)(ws + WS_CUR);
    int*   eids  = (int*)(ws + WS_EIDS);
    short* pk    = (short*)(ws + WS_PK);
    short* hb16  = (short*)(ws + WS_HB);

    hipMemsetAsync(d_out, 0, (size_t)out_size * sizeof(float), stream);
    hipMemsetAsync(cnt_i, 0, (size_t)NN * sizeof(int), stream);

    pack_weights<<<15, 256, 0, stream>>>(w_e1, w_e2, w_c1, w_f1, w_f2, pk);
    conv_h<<<3125, 256, 0, stream>>>(h, hb16);        // 6.4M elems / 8 / 256 = 3125 exact

    const int eb = (EE + 255) / 256;
    hist_kernel<<<eb, 256, 0, stream>>>(ei, cnt_i);
    scan_kernel<<<1, 1024, 0, stream>>>(cnt_i, off, cur);
    scatter_kernel<<<eb, 256, 0, stream>>>(ei, cur, eids);

    const int edge_waves = NB * (EE / 64);            // 31250
    const int edge_blocks = (edge_waves + 3) / 4;     // 7813
    edge_kernel<<<edge_blocks, 256, 0, stream>>>(
        hb16, x, ei, ea, eids, b_e1, b_e2, b_c1, w_c2, pk,
        smp, omp, agg, out_x);

    const int node_waves = NB * ((NN + 63) / 64);     // 1564
    const int node_blocks = (node_waves + 3) / 4;     // 391
    node_kernel<<<node_blocks, 256, 0, stream>>>(
        hb16, x, b_f1, b_f2, pk, off, agg, out_x);
}